// Round 1
// baseline (369.788 us; speedup 1.0000x reference)
//
#include <hip/hip_runtime.h>
#include <hip/hip_bf16.h>

#define ZD 64
#define HD 512
#define NB 256
#define KS 8
#define DIN 49152
#define DN 16384

typedef __attribute__((ext_vector_type(8))) short bf16x8;
typedef __attribute__((ext_vector_type(4))) float f32x4;

__device__ __forceinline__ ushort bfc(float x) {
  // f32 -> bf16 round-to-nearest-even (inputs are finite normals)
  uint u = __float_as_uint(x);
  uint r = (u + 0x7FFFu + ((u >> 16) & 1u)) >> 16;
  return (ushort)r;
}
__device__ __forceinline__ float softplusf_(float x) {
  return fmaxf(x, 0.f) + log1pf(expf(-fabsf(x)));
}
__device__ __forceinline__ float sigmoidf_(float x) {
  return 1.f / (1.f + expf(-x));
}

// ---------------- Stem GEMM: acc[b][h] = sum_k x[b][k] * Wstem[k][h] ----------------
// bf16 MFMA, BM=256 (full batch), BN=256, split-K S=128 (chunk=384), f32 atomicAdd.
#define SPLITS 128
#define KCH (DIN / SPLITS) /* 384 */
#define BKK 64

__global__ __launch_bounds__(512, 2)
void stem_kernel(const float* __restrict__ x, const float* __restrict__ W,
                 float* __restrict__ acc) {
  __shared__ ushort Ab[256][72];  // [row][k] bf16, padded 64->72 (2-way-ish banks)
  __shared__ ushort Bt[256][72];  // transposed: [n][k] bf16
  const int nt = blockIdx.x;      // 0..1  -> n-tile of 256
  const int sp = blockIdx.y;      // 0..SPLITS-1
  const int n0 = nt * 256;
  const int tid  = threadIdx.x;
  const int lane = tid & 63;
  const int wave = tid >> 6;           // 8 waves
  const int wm = wave >> 2, wn = wave & 3;  // wave tile: 128 rows x 64 cols

  f32x4 accr[8][4];
#pragma unroll
  for (int i = 0; i < 8; ++i)
#pragma unroll
    for (int j = 0; j < 4; ++j) accr[i][j] = (f32x4){0.f, 0.f, 0.f, 0.f};

  const int arow = tid >> 1, ahalf = tid & 1;  // A staging: 2 thr/row
  const int kp = tid >> 4, seg = tid & 15;     // B staging: k-pair, 16-col segment

#pragma unroll 1
  for (int it = 0; it < KCH / BKK; ++it) {
    const int k0 = sp * KCH + it * BKK;
    __syncthreads();
    {  // stage A (x rows, f32 -> bf16)
      const float4* src = (const float4*)(x + (size_t)arow * DIN + k0 + ahalf * 32);
      uint* dst = (uint*)&Ab[arow][ahalf * 32];
#pragma unroll
      for (int j = 0; j < 8; ++j) {
        float4 v = src[j];
        dst[2 * j]     = (uint)bfc(v.x) | ((uint)bfc(v.y) << 16);
        dst[2 * j + 1] = (uint)bfc(v.z) | ((uint)bfc(v.w) << 16);
      }
    }
    {  // stage B transposed (Wstem is k-major; frag reads need k-contiguous)
      const float4* r0 = (const float4*)(W + (size_t)(k0 + 2 * kp) * HD + n0 + seg * 16);
      const float4* r1 = (const float4*)(W + (size_t)(k0 + 2 * kp + 1) * HD + n0 + seg * 16);
#pragma unroll
      for (int jj = 0; jj < 4; ++jj) {
        float4 a = r0[jj], b = r1[jj];
        const float* ap = &a.x;
        const float* bp2 = &b.x;
#pragma unroll
        for (int c = 0; c < 4; ++c) {
          *(uint*)&Bt[seg * 16 + jj * 4 + c][2 * kp] =
              (uint)bfc(ap[c]) | ((uint)bfc(bp2[c]) << 16);
        }
      }
    }
    __syncthreads();
    const int rr = lane & 15;
#pragma unroll
    for (int ks = 0; ks < 2; ++ks) {
      // same per-lane k-mapping for A and B -> result invariant to HW k-order
      const int ko = ks * 32 + (lane >> 4) * 8;
      bf16x8 af[8], bfr[4];
#pragma unroll
      for (int mf = 0; mf < 8; ++mf)
        af[mf] = *(const bf16x8*)&Ab[wm * 128 + mf * 16 + rr][ko];
#pragma unroll
      for (int nf = 0; nf < 4; ++nf)
        bfr[nf] = *(const bf16x8*)&Bt[wn * 64 + nf * 16 + rr][ko];
#pragma unroll
      for (int mf = 0; mf < 8; ++mf)
#pragma unroll
        for (int nf = 0; nf < 4; ++nf)
          accr[mf][nf] = __builtin_amdgcn_mfma_f32_16x16x32_bf16(
              af[mf], bfr[nf], accr[mf][nf], 0, 0, 0);
    }
  }
  // C/D layout (HW-verified): col = lane&15, row = 4*(lane>>4) + i
  const int ccol = lane & 15, crow = (lane >> 4) * 4;
#pragma unroll
  for (int mf = 0; mf < 8; ++mf) {
#pragma unroll
    for (int nf = 0; nf < 4; ++nf) {
      const int col = n0 + wn * 64 + nf * 16 + ccol;
      const int row = wm * 128 + mf * 16 + crow;
#pragma unroll
      for (int i = 0; i < 4; ++i)
        atomicAdd(&acc[(row + i) * HD + col], accr[mf][nf][i]);
    }
  }
}

// ---------------- Fused head + recurrent scan: one block per batch row ----------------
__global__ __launch_bounds__(128)
void scan_kernel(const float* __restrict__ acc, const float* __restrict__ b_stem,
                 const float* __restrict__ Wg, const float* __restrict__ bg,
                 const float* __restrict__ Wihq, const float* __restrict__ bq,
                 const float* __restrict__ Wlinq, const float* __restrict__ blinq,
                 const float* __restrict__ Wihp, const float* __restrict__ bp,
                 const float* __restrict__ Wlinp, const float* __restrict__ blinp,
                 const float* __restrict__ eps0, const float* __restrict__ epsq,
                 float* __restrict__ zs, float* __restrict__ out_kl) {
  const int b = blockIdx.x, j = threadIdx.x;
  __shared__ float hf[HD], hfq[HD], g[HD];
  __shared__ float hbuf[128], encq[128], encp[128], zprev[ZD];

  for (int c = j; c < HD; c += 128) {
    float v = acc[b * HD + c] + b_stem[c];
    hf[c] = v > 0.f ? v : 0.f;
  }
  __syncthreads();
  {  // hfq = hf @ Wihq[0:512] + bq   (step-invariant gate contribution)
    const int c0 = j * 4;
    float4 a = *(const float4*)&bq[c0];
#pragma unroll 8
    for (int h = 0; h < HD; ++h) {
      float4 w = *(const float4*)&Wihq[h * HD + c0];
      float hv = hf[h];
      a.x += hv * w.x; a.y += hv * w.y; a.z += hv * w.z; a.w += hv * w.w;
    }
    *(float4*)&hfq[c0] = a;
  }
  {  // enc = hf @ Wg + bg
    float a = bg[j];
#pragma unroll 8
    for (int h = 0; h < HD; ++h) a += hf[h] * Wg[h * 128 + j];
    encq[j] = a;
  }
  __syncthreads();
  if (j < ZD) {
    float mu = encq[j], lv = encq[ZD + j];
    float s0 = softplusf_(lv + 0.5f) + 1e-8f;
    float z0 = mu + s0 * eps0[b * ZD + j];
    zs[b * ZD + j] = z0;
    zprev[j] = z0;
    out_kl[(b * ZD + j) * KS] = -logf(s0) + (s0 * s0 + mu * mu) * 0.5f - 0.5f;
  }
  __syncthreads();

  for (int t = 0; t < KS - 1; ++t) {
    {  // posterior gates: hfq + zprev @ Wihq[512:576]
      const int c0 = j * 4;
      float4 a = *(const float4*)&hfq[c0];
#pragma unroll 8
      for (int z = 0; z < ZD; ++z) {
        float4 w = *(const float4*)&Wihq[(HD + z) * HD + c0];
        float zv = zprev[z];
        a.x += zv * w.x; a.y += zv * w.y; a.z += zv * w.z; a.w += zv * w.w;
      }
      *(float4*)&g[c0] = a;
    }
    __syncthreads();
    {  // LSTM (zero state): c = sig(i)*tanh(g), h = sig(o)*tanh(c)
      float cs = sigmoidf_(g[j]) * tanhf(g[256 + j]);
      hbuf[j] = sigmoidf_(g[384 + j]) * tanhf(cs);
    }
    __syncthreads();
    {  // enc_q = hq @ Wlinq + blinq
      float a = blinq[j];
#pragma unroll 8
      for (int k = 0; k < 128; ++k) a += hbuf[k] * Wlinq[k * 128 + j];
      encq[j] = a;
    }
    {  // prior gates: bp + zprev @ Wihp   (g's readers already synced past)
      const int c0 = j * 4;
      float4 a = *(const float4*)&bp[c0];
#pragma unroll 8
      for (int z = 0; z < ZD; ++z) {
        float4 w = *(const float4*)&Wihp[z * HD + c0];
        float zv = zprev[z];
        a.x += zv * w.x; a.y += zv * w.y; a.z += zv * w.z; a.w += zv * w.w;
      }
      *(float4*)&g[c0] = a;
    }
    __syncthreads();
    {
      float cs = sigmoidf_(g[j]) * tanhf(g[256 + j]);
      hbuf[j] = sigmoidf_(g[384 + j]) * tanhf(cs);
    }
    __syncthreads();
    {  // enc_p = hp @ Wlinp + blinp
      float a = blinp[j];
#pragma unroll 8
      for (int k = 0; k < 128; ++k) a += hbuf[k] * Wlinp[k * 128 + j];
      encp[j] = a;
    }
    __syncthreads();
    if (j < ZD) {
      float mq = encq[j], lq = encq[ZD + j];
      float sq = softplusf_(lq + 0.5f) + 1e-8f;
      float zq = mq + sq * epsq[(t * NB + b) * ZD + j];
      float mp = encp[j], lp = encp[ZD + j];
      float spv = softplusf_(lp + 0.5f) + 1e-8f;
      float d = mq - mp;
      out_kl[(b * ZD + j) * KS + t + 1] =
          logf(spv / sq) + (sq * sq + d * d) / (2.f * spv * spv) - 0.5f;
      zs[(size_t)(t + 1) * NB * ZD + b * ZD + j] = zq;
      zprev[j] = zq;
    }
    __syncthreads();
  }
}

// -------- Decoder: dec = zs@Wdec + bdec; log-sigmoid; exclusive cumsum over k --------
__global__ __launch_bounds__(256)
void dec_kernel(const float* __restrict__ zs, const float* __restrict__ Wd,
                const float* __restrict__ bd, float* __restrict__ out) {
  const int pt = blockIdx.x;  // 0..7   -> 2048-wide p tile
  const int bg = blockIdx.y;  // 0..63  -> 4 batch rows
  const int tid = threadIdx.x;
  const int p0 = pt * 2048 + tid * 8;
  __shared__ float zsh[KS][ZD];
  float bde[8];
  *(float4*)&bde[0] = *(const float4*)&bd[p0];
  *(float4*)&bde[4] = *(const float4*)&bd[p0 + 4];
  for (int bs = 0; bs < 4; ++bs) {
    const int b = bg * 4 + bs;
    __syncthreads();
    if (tid < 128)
      ((float4*)zsh)[tid] =
          *(const float4*)&zs[(size_t)(tid >> 4) * NB * ZD + b * ZD + (tid & 15) * 4];
    __syncthreads();
    float av[KS][8];
#pragma unroll
    for (int k = 0; k < KS; ++k)
#pragma unroll
      for (int i = 0; i < 8; ++i) av[k][i] = 0.f;
    for (int z = 0; z < ZD; ++z) {
      float4 w0 = *(const float4*)&Wd[(size_t)z * DN + p0];
      float4 w1 = *(const float4*)&Wd[(size_t)z * DN + p0 + 4];
#pragma unroll
      for (int k = 0; k < KS; ++k) {
        float zv = zsh[k][z];
        av[k][0] += zv * w0.x; av[k][1] += zv * w0.y;
        av[k][2] += zv * w0.z; av[k][3] += zv * w0.w;
        av[k][4] += zv * w1.x; av[k][5] += zv * w1.y;
        av[k][6] += zv * w1.z; av[k][7] += zv * w1.w;
      }
    }
    float run[8];
#pragma unroll
    for (int i = 0; i < 8; ++i) run[i] = 0.f;
#pragma unroll
    for (int k = 0; k < KS; ++k) {
      float ov[8];
#pragma unroll
      for (int i = 0; i < 8; ++i) {
        float dec = av[k][i] + bde[i];
        float spd = softplusf_(dec);       // softplus(dec)
        ov[i] = run[i] + (dec - spd);      // excl-cumsum(lns) + log_sigmoid(dec)
        run[i] -= spd;                     // accumulate lns = -softplus(dec)
      }
      float4 o0 = {ov[0], ov[1], ov[2], ov[3]};
      float4 o1 = {ov[4], ov[5], ov[6], ov[7]};
      *(float4*)&out[(size_t)(k * NB + b) * DN + p0] = o0;
      *(float4*)&out[(size_t)(k * NB + b) * DN + p0 + 4] = o1;
    }
  }
}

extern "C" void kernel_launch(void* const* d_in, const int* in_sizes, int n_in,
                              void* d_out, int out_size, void* d_ws, size_t ws_size,
                              hipStream_t stream) {
  (void)in_sizes; (void)n_in; (void)out_size; (void)ws_size;
  const float* x     = (const float*)d_in[0];
  // d_in[1] = K (always 8, hardcoded)
  const float* eps0  = (const float*)d_in[2];
  const float* epsq  = (const float*)d_in[3];
  // d_in[4] = eps_p : unused by the reference (prior is never sampled)
  const float* Wstem = (const float*)d_in[5];
  const float* bstem = (const float*)d_in[6];
  const float* Wg    = (const float*)d_in[7];
  const float* bgp   = (const float*)d_in[8];
  const float* Wihq  = (const float*)d_in[9];
  const float* bq    = (const float*)d_in[10];
  const float* Wlinq = (const float*)d_in[11];
  const float* blinq = (const float*)d_in[12];
  const float* Wihp  = (const float*)d_in[13];
  const float* bp    = (const float*)d_in[14];
  const float* Wlinp = (const float*)d_in[15];
  const float* blinp = (const float*)d_in[16];
  const float* Wd    = (const float*)d_in[17];
  const float* bd    = (const float*)d_in[18];

  float* out    = (float*)d_out;
  float* outkl  = out + (size_t)KS * NB * DN;   // 33,554,432
  float* accbuf = (float*)d_ws;                 // 256*512 f32
  float* zsbuf  = accbuf + NB * HD;             // 8*256*64 f32

  hipMemsetAsync(accbuf, 0, (size_t)NB * HD * sizeof(float), stream);
  stem_kernel<<<dim3(2, SPLITS), 512, 0, stream>>>(x, Wstem, accbuf);
  scan_kernel<<<NB, 128, 0, stream>>>(accbuf, bstem, Wg, bgp, Wihq, bq, Wlinq, blinq,
                                      Wihp, bp, Wlinp, blinp, eps0, epsq, zsbuf, outkl);
  dec_kernel<<<dim3(8, 64), 256, 0, stream>>>(zsbuf, Wd, bd, out);
}

// Round 3
// 322.480 us; speedup vs baseline: 1.1467x; 1.1467x over previous
//
#include <hip/hip_runtime.h>
#include <hip/hip_bf16.h>

#define ZD 64
#define HD 512
#define NB 256
#define KS 8
#define DIN 49152
#define DN 16384

typedef __attribute__((ext_vector_type(8))) short bf16x8;
typedef __attribute__((ext_vector_type(4))) float f32x4;

__device__ __forceinline__ ushort bfc(float x) {
  // f32 -> bf16 round-to-nearest-even (inputs are finite normals)
  uint u = __float_as_uint(x);
  uint r = (u + 0x7FFFu + ((u >> 16) & 1u)) >> 16;
  return (ushort)r;
}
__device__ __forceinline__ float softplusf_(float x) {
  return fmaxf(x, 0.f) + log1pf(expf(-fabsf(x)));
}
__device__ __forceinline__ float sigmoidf_(float x) {
  return 1.f / (1.f + expf(-x));
}

// ---------------- Stem GEMM: acc[b][h] = sum_k x[b][k] * Wstem[k][h] ----------------
// bf16 MFMA, BM=256 (full batch), BN=256, split-K S=128 (chunk=384), f32 atomicAdd.
#define SPLITS 128
#define KCH (DIN / SPLITS) /* 384 */
#define BKK 64

__global__ __launch_bounds__(512, 2)
void stem_kernel(const float* __restrict__ x, const float* __restrict__ W,
                 float* __restrict__ acc) {
  __shared__ ushort Ab[256][72];  // [row][k] bf16, padded
  __shared__ ushort Bt[256][72];  // transposed: [n][k] bf16
  const int nt = blockIdx.x;      // 0..1  -> n-tile of 256
  const int sp = blockIdx.y;      // 0..SPLITS-1
  const int n0 = nt * 256;
  const int tid  = threadIdx.x;
  const int lane = tid & 63;
  const int wave = tid >> 6;           // 8 waves
  const int wm = wave >> 2, wn = wave & 3;  // wave tile: 128 rows x 64 cols

  f32x4 accr[8][4];
#pragma unroll
  for (int i = 0; i < 8; ++i)
#pragma unroll
    for (int j = 0; j < 4; ++j) accr[i][j] = (f32x4){0.f, 0.f, 0.f, 0.f};

  const int arow = tid >> 1, ahalf = tid & 1;  // A staging: 2 thr/row
  const int kp = tid >> 4, seg = tid & 15;     // B staging: k-pair, 16-col segment

#pragma unroll 1
  for (int it = 0; it < KCH / BKK; ++it) {
    const int k0 = sp * KCH + it * BKK;
    __syncthreads();
    {  // stage A (x rows, f32 -> bf16)
      const float4* src = (const float4*)(x + (size_t)arow * DIN + k0 + ahalf * 32);
      uint* dst = (uint*)&Ab[arow][ahalf * 32];
#pragma unroll
      for (int j = 0; j < 8; ++j) {
        float4 v = src[j];
        dst[2 * j]     = (uint)bfc(v.x) | ((uint)bfc(v.y) << 16);
        dst[2 * j + 1] = (uint)bfc(v.z) | ((uint)bfc(v.w) << 16);
      }
    }
    {  // stage B transposed (Wstem is k-major; frag reads need k-contiguous)
      const float4* r0 = (const float4*)(W + (size_t)(k0 + 2 * kp) * HD + n0 + seg * 16);
      const float4* r1 = (const float4*)(W + (size_t)(k0 + 2 * kp + 1) * HD + n0 + seg * 16);
#pragma unroll
      for (int jj = 0; jj < 4; ++jj) {
        float4 a = r0[jj], b = r1[jj];
        const float* ap = &a.x;
        const float* bp2 = &b.x;
#pragma unroll
        for (int c = 0; c < 4; ++c) {
          *(uint*)&Bt[seg * 16 + jj * 4 + c][2 * kp] =
              (uint)bfc(ap[c]) | ((uint)bfc(bp2[c]) << 16);
        }
      }
    }
    __syncthreads();
    const int rr = lane & 15;
#pragma unroll
    for (int ks = 0; ks < 2; ++ks) {
      // same per-lane k-mapping for A and B -> result invariant to HW k-order
      const int ko = ks * 32 + (lane >> 4) * 8;
      bf16x8 af[8], bfr[4];
#pragma unroll
      for (int mf = 0; mf < 8; ++mf)
        af[mf] = *(const bf16x8*)&Ab[wm * 128 + mf * 16 + rr][ko];
#pragma unroll
      for (int nf = 0; nf < 4; ++nf)
        bfr[nf] = *(const bf16x8*)&Bt[wn * 64 + nf * 16 + rr][ko];
#pragma unroll
      for (int mf = 0; mf < 8; ++mf)
#pragma unroll
        for (int nf = 0; nf < 4; ++nf)
          accr[mf][nf] = __builtin_amdgcn_mfma_f32_16x16x32_bf16(
              af[mf], bfr[nf], accr[mf][nf], 0, 0, 0);
    }
  }
  // C/D layout (HW-verified): col = lane&15, row = 4*(lane>>4) + i
  const int ccol = lane & 15, crow = (lane >> 4) * 4;
#pragma unroll
  for (int mf = 0; mf < 8; ++mf) {
#pragma unroll
    for (int nf = 0; nf < 4; ++nf) {
      const int col = n0 + wn * 64 + nf * 16 + ccol;
      const int row = wm * 128 + mf * 16 + crow;
#pragma unroll
      for (int i = 0; i < 4; ++i)
        atomicAdd(&acc[(row + i) * HD + col], accr[mf][nf][i]);
    }
  }
}

// ---------------- Fused head + recurrent scan: one block per batch row ----------------
// zsb: bf16 z-samples, M-row ordering m = b*8 + k -> zsb[m*64 + j]
__global__ __launch_bounds__(128)
void scan_kernel(const float* __restrict__ acc, const float* __restrict__ b_stem,
                 const float* __restrict__ Wg, const float* __restrict__ bg,
                 const float* __restrict__ Wihq, const float* __restrict__ bq,
                 const float* __restrict__ Wlinq, const float* __restrict__ blinq,
                 const float* __restrict__ Wihp, const float* __restrict__ bp,
                 const float* __restrict__ Wlinp, const float* __restrict__ blinp,
                 const float* __restrict__ eps0, const float* __restrict__ epsq,
                 ushort* __restrict__ zsb, float* __restrict__ out_kl) {
  const int b = blockIdx.x, j = threadIdx.x;
  __shared__ float hf[HD], hfq[HD], g[HD];
  __shared__ float hbuf[128], encq[128], encp[128], zprev[ZD];

  for (int c = j; c < HD; c += 128) {
    float v = acc[b * HD + c] + b_stem[c];
    hf[c] = v > 0.f ? v : 0.f;
  }
  __syncthreads();
  {  // hfq = hf @ Wihq[0:512] + bq   (step-invariant gate contribution)
    const int c0 = j * 4;
    float4 a = *(const float4*)&bq[c0];
#pragma unroll 8
    for (int h = 0; h < HD; ++h) {
      float4 w = *(const float4*)&Wihq[h * HD + c0];
      float hv = hf[h];
      a.x += hv * w.x; a.y += hv * w.y; a.z += hv * w.z; a.w += hv * w.w;
    }
    *(float4*)&hfq[c0] = a;
  }
  {  // enc = hf @ Wg + bg
    float a = bg[j];
#pragma unroll 8
    for (int h = 0; h < HD; ++h) a += hf[h] * Wg[h * 128 + j];
    encq[j] = a;
  }
  __syncthreads();
  if (j < ZD) {
    float mu = encq[j], lv = encq[ZD + j];
    float s0 = softplusf_(lv + 0.5f) + 1e-8f;
    float z0 = mu + s0 * eps0[b * ZD + j];
    zsb[(b * KS) * ZD + j] = bfc(z0);
    zprev[j] = z0;
    out_kl[(b * ZD + j) * KS] = -logf(s0) + (s0 * s0 + mu * mu) * 0.5f - 0.5f;
  }
  __syncthreads();

  for (int t = 0; t < KS - 1; ++t) {
    {  // posterior gates: hfq + zprev @ Wihq[512:576]
      const int c0 = j * 4;
      float4 a = *(const float4*)&hfq[c0];
#pragma unroll 8
      for (int z = 0; z < ZD; ++z) {
        float4 w = *(const float4*)&Wihq[(HD + z) * HD + c0];
        float zv = zprev[z];
        a.x += zv * w.x; a.y += zv * w.y; a.z += zv * w.z; a.w += zv * w.w;
      }
      *(float4*)&g[c0] = a;
    }
    __syncthreads();
    {  // LSTM (zero state): c = sig(i)*tanh(g), h = sig(o)*tanh(c)
      float cs = sigmoidf_(g[j]) * tanhf(g[256 + j]);
      hbuf[j] = sigmoidf_(g[384 + j]) * tanhf(cs);
    }
    __syncthreads();
    {  // enc_q = hq @ Wlinq + blinq
      float a = blinq[j];
#pragma unroll 8
      for (int k = 0; k < 128; ++k) a += hbuf[k] * Wlinq[k * 128 + j];
      encq[j] = a;
    }
    {  // prior gates: bp + zprev @ Wihp
      const int c0 = j * 4;
      float4 a = *(const float4*)&bp[c0];
#pragma unroll 8
      for (int z = 0; z < ZD; ++z) {
        float4 w = *(const float4*)&Wihp[z * HD + c0];
        float zv = zprev[z];
        a.x += zv * w.x; a.y += zv * w.y; a.z += zv * w.z; a.w += zv * w.w;
      }
      *(float4*)&g[c0] = a;
    }
    __syncthreads();
    {
      float cs = sigmoidf_(g[j]) * tanhf(g[256 + j]);
      hbuf[j] = sigmoidf_(g[384 + j]) * tanhf(cs);
    }
    __syncthreads();
    {  // enc_p = hp @ Wlinp + blinp
      float a = blinp[j];
#pragma unroll 8
      for (int k = 0; k < 128; ++k) a += hbuf[k] * Wlinp[k * 128 + j];
      encp[j] = a;
    }
    __syncthreads();
    if (j < ZD) {
      float mq = encq[j], lq = encq[ZD + j];
      float sq = softplusf_(lq + 0.5f) + 1e-8f;
      float zq = mq + sq * epsq[(t * NB + b) * ZD + j];
      float mp = encp[j], lp = encp[ZD + j];
      float spv = softplusf_(lp + 0.5f) + 1e-8f;
      float d = mq - mp;
      out_kl[(b * ZD + j) * KS + t + 1] =
          logf(spv / sq) + (sq * sq + d * d) / (2.f * spv * spv) - 0.5f;
      zsb[(b * KS + t + 1) * ZD + j] = bfc(zq);
      zprev[j] = zq;
    }
    __syncthreads();
  }
}

// -------- W_dec transpose to bf16: WdT[col*64 + k] = bf16(Wd[k*DN + col]) --------
__global__ __launch_bounds__(256)
void wdt_kernel(const float* __restrict__ Wd, ushort* __restrict__ WdT) {
  const int c = blockIdx.x * 256 + threadIdx.x;
  uint packed[32];
#pragma unroll
  for (int k = 0; k < 32; ++k) {
    float a = Wd[(size_t)(2 * k) * DN + c];
    float b = Wd[(size_t)(2 * k + 1) * DN + c];
    packed[k] = (uint)bfc(a) | ((uint)bfc(b) << 16);
  }
  uint4* dst = (uint4*)&WdT[(size_t)c * 64];
#pragma unroll
  for (int i = 0; i < 8; ++i)
    dst[i] = make_uint4(packed[4 * i], packed[4 * i + 1], packed[4 * i + 2],
                        packed[4 * i + 3]);
}

// -------- Decoder: MFMA GEMM [2048 x 16384 x 64] + log-sigmoid + excl k-cumsum --------
// M-row m = b*8 + k. No LDS, no barriers; fragments loaded straight from global.
// Each wave computes a 16x64 tile: 4 n-fragments of 16 cols each.
__global__ __launch_bounds__(256)
void dec_kernel(const ushort* __restrict__ zsb, const ushort* __restrict__ WdT,
                const float* __restrict__ bd, float* __restrict__ out) {
  const int tid = threadIdx.x;
  const int lane = tid & 63;
  const int wave = tid >> 6;                    // 0..3
  const int rr = lane & 15, gq = lane >> 4;     // frag row-sel / k-slot group
  const int mtile = blockIdx.y * 16;            // 2048/16 = 128 tiles
  const int ncol0 = blockIdx.x * 256 + wave * 64;  // block covers 256 cols, wave 64

  // A fragments: rows mtile+rr, k-slots gq*8 + 32*ks (same mapping as B -> k-order safe)
  bf16x8 af[2];
#pragma unroll
  for (int ks2 = 0; ks2 < 2; ++ks2)
    af[ks2] = *(const bf16x8*)&zsb[(size_t)(mtile + rr) * 64 + ks2 * 32 + gq * 8];

  f32x4 acc[4];
#pragma unroll
  for (int nf = 0; nf < 4; ++nf) acc[nf] = (f32x4){0.f, 0.f, 0.f, 0.f};

#pragma unroll
  for (int ks2 = 0; ks2 < 2; ++ks2) {
#pragma unroll
    for (int nf = 0; nf < 4; ++nf) {
      bf16x8 bf = *(const bf16x8*)&WdT[(size_t)(ncol0 + nf * 16 + rr) * 64 +
                                       ks2 * 32 + gq * 8];
      acc[nf] = __builtin_amdgcn_mfma_f32_16x16x32_bf16(af[ks2], bf, acc[nf], 0, 0, 0);
    }
  }

  // Epilogue: C row = 4*gq + i (global m = mtile + 4*gq + i), col = ncol0+nf*16+rr.
  // m = b*8 + k: gq in {0,2} -> k = i (low half), gq in {1,3} -> k = 4+i (high half).
  const int bb = (mtile >> 3) + (gq >> 1);
  const int khi = (gq & 1) * 4;
#pragma unroll
  for (int nf = 0; nf < 4; ++nf) {
    const int col = ncol0 + nf * 16 + rr;
    const float bde = bd[col];
    float run = 0.f;
    float ov[4];
#pragma unroll
    for (int i = 0; i < 4; ++i) {
      float dec = acc[nf][i] + bde;
      float spd = softplusf_(dec);
      ov[i] = run + (dec - spd);   // excl-cumsum(lns) + log_sigmoid(dec)
      run -= spd;                  // lns = -softplus(dec)
    }
    // pass low-half (k0-3) lns total to the high-half lanes (lane^16 flips gq bit 0)
    float prev = __shfl_xor(run, 16, 64);
    float base = (gq & 1) ? prev : 0.f;
#pragma unroll
    for (int i = 0; i < 4; ++i) {
      const int k = khi + i;
      out[((size_t)k * NB + bb) * DN + col] = ov[i] + base;
    }
  }
}

extern "C" void kernel_launch(void* const* d_in, const int* in_sizes, int n_in,
                              void* d_out, int out_size, void* d_ws, size_t ws_size,
                              hipStream_t stream) {
  (void)in_sizes; (void)n_in; (void)out_size; (void)ws_size;
  const float* x     = (const float*)d_in[0];
  // d_in[1] = K (always 8, hardcoded)
  const float* eps0  = (const float*)d_in[2];
  const float* epsq  = (const float*)d_in[3];
  // d_in[4] = eps_p : unused by the reference
  const float* Wstem = (const float*)d_in[5];
  const float* bstem = (const float*)d_in[6];
  const float* Wg    = (const float*)d_in[7];
  const float* bgp   = (const float*)d_in[8];
  const float* Wihq  = (const float*)d_in[9];
  const float* bq    = (const float*)d_in[10];
  const float* Wlinq = (const float*)d_in[11];
  const float* blinq = (const float*)d_in[12];
  const float* Wihp  = (const float*)d_in[13];
  const float* bp    = (const float*)d_in[14];
  const float* Wlinp = (const float*)d_in[15];
  const float* blinp = (const float*)d_in[16];
  const float* Wd    = (const float*)d_in[17];
  const float* bd    = (const float*)d_in[18];

  float* out    = (float*)d_out;
  float* outkl  = out + (size_t)KS * NB * DN;
  float* accbuf = (float*)d_ws;                        // 256*512 f32 = 512 KB
  ushort* zsb   = (ushort*)(accbuf + NB * HD);         // 2048*64 bf16 = 256 KB
  ushort* wdt   = zsb + (size_t)KS * NB * ZD;          // 16384*64 bf16 = 2 MB

  hipMemsetAsync(accbuf, 0, (size_t)NB * HD * sizeof(float), stream);
  wdt_kernel<<<DN / 256, 256, 0, stream>>>(Wd, wdt);
  stem_kernel<<<dim3(2, SPLITS), 512, 0, stream>>>(x, Wstem, accbuf);
  scan_kernel<<<NB, 128, 0, stream>>>(accbuf, bstem, Wg, bgp, Wihq, bq, Wlinq, blinq,
                                      Wihp, bp, Wlinp, blinp, eps0, epsq, zsb, outkl);
  // grid.x: 16384 / 256 cols-per-block = 64;  grid.y: 2048 rows / 16 = 128
  dec_kernel<<<dim3(64, 128), 256, 0, stream>>>(zsb, wdt, bd, out);
}

// Round 4
// 247.389 us; speedup vs baseline: 1.4948x; 1.3035x over previous
//
#include <hip/hip_runtime.h>
#include <hip/hip_bf16.h>

#define ZD 64
#define HD 512
#define NB 256
#define KS 8
#define DIN 49152
#define DN 16384

typedef __attribute__((ext_vector_type(8))) short bf16x8;
typedef __attribute__((ext_vector_type(4))) float f32x4;

__device__ __forceinline__ ushort bfc(float x) {
  uint u = __float_as_uint(x);
  uint r = (u + 0x7FFFu + ((u >> 16) & 1u)) >> 16;
  return (ushort)r;
}
__device__ __forceinline__ uint pk2(float a, float b) {
  return (uint)bfc(a) | ((uint)bfc(b) << 16);
}
__device__ __forceinline__ float lof(uint u) { return __uint_as_float(u << 16); }
__device__ __forceinline__ float hif(uint u) { return __uint_as_float(u & 0xFFFF0000u); }
__device__ __forceinline__ float softplusf_(float x) {
  return fmaxf(x, 0.f) + log1pf(expf(-fabsf(x)));
}
__device__ __forceinline__ float sigmoidf_(float x) {
  return 1.f / (1.f + expf(-x));
}

// ---------------- Stem GEMM: acc[b][h] = sum_k x[b][k] * Wstem[k][h] ----------------
#define SPLITS 128
#define KCH (DIN / SPLITS) /* 384 */
#define BKK 64

__global__ __launch_bounds__(512, 2)
void stem_kernel(const float* __restrict__ x, const float* __restrict__ W,
                 float* __restrict__ acc) {
  __shared__ ushort Ab[256][72];
  __shared__ ushort Bt[256][72];
  const int nt = blockIdx.x;
  const int sp = blockIdx.y;
  const int n0 = nt * 256;
  const int tid  = threadIdx.x;
  const int lane = tid & 63;
  const int wave = tid >> 6;
  const int wm = wave >> 2, wn = wave & 3;

  f32x4 accr[8][4];
#pragma unroll
  for (int i = 0; i < 8; ++i)
#pragma unroll
    for (int j = 0; j < 4; ++j) accr[i][j] = (f32x4){0.f, 0.f, 0.f, 0.f};

  const int arow = tid >> 1, ahalf = tid & 1;
  const int kp = tid >> 4, seg = tid & 15;

#pragma unroll 1
  for (int it = 0; it < KCH / BKK; ++it) {
    const int k0 = sp * KCH + it * BKK;
    __syncthreads();
    {
      const float4* src = (const float4*)(x + (size_t)arow * DIN + k0 + ahalf * 32);
      uint* dst = (uint*)&Ab[arow][ahalf * 32];
#pragma unroll
      for (int j = 0; j < 8; ++j) {
        float4 v = src[j];
        dst[2 * j]     = pk2(v.x, v.y);
        dst[2 * j + 1] = pk2(v.z, v.w);
      }
    }
    {
      const float4* r0 = (const float4*)(W + (size_t)(k0 + 2 * kp) * HD + n0 + seg * 16);
      const float4* r1 = (const float4*)(W + (size_t)(k0 + 2 * kp + 1) * HD + n0 + seg * 16);
#pragma unroll
      for (int jj = 0; jj < 4; ++jj) {
        float4 a = r0[jj], b = r1[jj];
        const float* ap = &a.x;
        const float* bp2 = &b.x;
#pragma unroll
        for (int c = 0; c < 4; ++c) {
          *(uint*)&Bt[seg * 16 + jj * 4 + c][2 * kp] = pk2(ap[c], bp2[c]);
        }
      }
    }
    __syncthreads();
    const int rr = lane & 15;
#pragma unroll
    for (int ks = 0; ks < 2; ++ks) {
      const int ko = ks * 32 + (lane >> 4) * 8;
      bf16x8 af[8], bfr[4];
#pragma unroll
      for (int mf = 0; mf < 8; ++mf)
        af[mf] = *(const bf16x8*)&Ab[wm * 128 + mf * 16 + rr][ko];
#pragma unroll
      for (int nf = 0; nf < 4; ++nf)
        bfr[nf] = *(const bf16x8*)&Bt[wn * 64 + nf * 16 + rr][ko];
#pragma unroll
      for (int mf = 0; mf < 8; ++mf)
#pragma unroll
        for (int nf = 0; nf < 4; ++nf)
          accr[mf][nf] = __builtin_amdgcn_mfma_f32_16x16x32_bf16(
              af[mf], bfr[nf], accr[mf][nf], 0, 0, 0);
    }
  }
  const int ccol = lane & 15, crow = (lane >> 4) * 4;
#pragma unroll
  for (int mf = 0; mf < 8; ++mf) {
#pragma unroll
    for (int nf = 0; nf < 4; ++nf) {
      const int col = n0 + wn * 64 + nf * 16 + ccol;
      const int row = wm * 128 + mf * 16 + crow;
#pragma unroll
      for (int i = 0; i < 4; ++i)
        atomicAdd(&acc[(row + i) * HD + col], accr[mf][nf][i]);
    }
  }
}

// ---- WcombT: bf16 [640 cols][512 k] of B = [Wihq[:512] | Wg] (64x64 tile transpose) ----
__global__ __launch_bounds__(256)
void wcombT_kernel(const float* __restrict__ Wihq, const float* __restrict__ Wg,
                   ushort* __restrict__ WcT) {
  __shared__ float T[64][68];
  const int bx = blockIdx.x;  // col tile 0..9
  const int by = blockIdx.y;  // k tile 0..7
  const int t = threadIdx.x;
  const int ct = bx * 64, kt = by * 64;
  {
    const int rl = t >> 2, cq = (t & 3) * 16;
    const float* src = (bx < 8) ? &Wihq[(size_t)(kt + rl) * 512 + ct + cq]
                                : &Wg[(size_t)(kt + rl) * 128 + (ct - 512) + cq];
#pragma unroll
    for (int i = 0; i < 4; ++i) {
      float4 v = *(const float4*)(src + 4 * i);
      T[rl][cq + 4 * i + 0] = v.x;
      T[rl][cq + 4 * i + 1] = v.y;
      T[rl][cq + 4 * i + 2] = v.z;
      T[rl][cq + 4 * i + 3] = v.w;
    }
  }
  __syncthreads();
  {
    const int cl = t >> 2, kq = (t & 3) * 16;
    uint* dst = (uint*)WcT;
#pragma unroll
    for (int i = 0; i < 8; ++i) {
      uint u = pk2(T[kq + 2 * i][cl], T[kq + 2 * i + 1][cl]);
      dst[(((size_t)(ct + cl)) * 512 + kt + kq + 2 * i) >> 1] = u;
    }
  }
}

// ---- gemmA: hf = relu(acc+bstem); hfqg = hf@Wihq[:512]+bq ; enc0g = hf@Wg+bg ----
// M=256, N=640, K=512. Register-fragment MFMA (dec_kernel pattern, validated).
__global__ __launch_bounds__(256)
void gemmA_kernel(const float* __restrict__ acc, const float* __restrict__ bstem,
                  const ushort* __restrict__ WcT, const float* __restrict__ bq,
                  const float* __restrict__ bg, float* __restrict__ hfqg,
                  float* __restrict__ enc0g) {
  const int tid = threadIdx.x;
  const int lane = tid & 63;
  const int wave = tid >> 6;
  const int rr = lane & 15, gq = lane >> 4;
  const int mtile = blockIdx.y * 16;          // 16 tiles
  const int ncol = blockIdx.x * 64 + wave * 16;  // 10 * 64 = 640
  const int row = mtile + rr;

  f32x4 a4 = (f32x4){0.f, 0.f, 0.f, 0.f};
#pragma unroll
  for (int ks2 = 0; ks2 < 16; ++ks2) {
    const int k0 = ks2 * 32 + gq * 8;
    float4 x0 = *(const float4*)&acc[(size_t)row * HD + k0];
    float4 x1 = *(const float4*)&acc[(size_t)row * HD + k0 + 4];
    float4 b0 = *(const float4*)&bstem[k0];
    float4 b1 = *(const float4*)&bstem[k0 + 4];
    bf16x8 af;
    af[0] = (short)bfc(fmaxf(x0.x + b0.x, 0.f));
    af[1] = (short)bfc(fmaxf(x0.y + b0.y, 0.f));
    af[2] = (short)bfc(fmaxf(x0.z + b0.z, 0.f));
    af[3] = (short)bfc(fmaxf(x0.w + b0.w, 0.f));
    af[4] = (short)bfc(fmaxf(x1.x + b1.x, 0.f));
    af[5] = (short)bfc(fmaxf(x1.y + b1.y, 0.f));
    af[6] = (short)bfc(fmaxf(x1.z + b1.z, 0.f));
    af[7] = (short)bfc(fmaxf(x1.w + b1.w, 0.f));
    bf16x8 bf = *(const bf16x8*)&WcT[(size_t)(ncol + rr) * 512 + k0];
    a4 = __builtin_amdgcn_mfma_f32_16x16x32_bf16(af, bf, a4, 0, 0, 0);
  }
  const int col = ncol + rr;  // C col = lane&15 = rr
  if (col < 512) {
    const float bb = bq[col];
#pragma unroll
    for (int i = 0; i < 4; ++i)
      hfqg[(size_t)(mtile + 4 * gq + i) * HD + col] = a4[i] + bb;
  } else {
    const float bb = bg[col - 512];
#pragma unroll
    for (int i = 0; i < 4; ++i)
      enc0g[(size_t)(mtile + 4 * gq + i) * 128 + (col - 512)] = a4[i] + bb;
  }
}

// ---------------- Recurrent scan: one block (512 thr) per batch row ----------------
// Gate weights in registers (bf16-packed); Wlin in LDS (bf16-packed); eps in LDS.
__global__ __launch_bounds__(512, 2)
void scan_kernel(const float* __restrict__ hfqg, const float* __restrict__ enc0g,
                 const float* __restrict__ Wihq, const float* __restrict__ Wihp,
                 const float* __restrict__ Wlinq, const float* __restrict__ blinq,
                 const float* __restrict__ Wlinp, const float* __restrict__ blinp,
                 const float* __restrict__ bp,
                 const float* __restrict__ eps0, const float* __restrict__ epsq,
                 ushort* __restrict__ zsb, float* __restrict__ out_kl) {
  const int b = blockIdx.x, tid = threadIdx.x;
  __shared__ uint WlL[2][64 * 128];  // bf16-packed k-pairs: [q|p][kp2*128 + j]
  __shared__ float g[512], gp[512];
  __shared__ float hq[128], hp[128];
  __shared__ float psum[512];
  __shared__ float zsh[64];
  __shared__ float epsL[448];

  // z-gate weights -> registers (bf16 pairs), statically indexed
  uint wq[32], wp[32];
#pragma unroll
  for (int zp = 0; zp < 32; ++zp) {
    wq[zp] = pk2(Wihq[(size_t)(HD + 2 * zp) * HD + tid],
                 Wihq[(size_t)(HD + 2 * zp + 1) * HD + tid]);
    wp[zp] = pk2(Wihp[(size_t)(2 * zp) * HD + tid],
                 Wihp[(size_t)(2 * zp + 1) * HD + tid]);
  }
  // Wlin -> LDS packed
#pragma unroll
  for (int i = 0; i < 16; ++i) {
    int idx = i * 512 + tid;        // 0..8191
    int kp2 = idx >> 7, jj = idx & 127;
    WlL[0][idx] = pk2(Wlinq[(2 * kp2) * 128 + jj], Wlinq[(2 * kp2 + 1) * 128 + jj]);
    WlL[1][idx] = pk2(Wlinp[(2 * kp2) * 128 + jj], Wlinp[(2 * kp2 + 1) * 128 + jj]);
  }
  if (tid < 448) epsL[tid] = epsq[(size_t)((tid >> 6) * NB + b) * ZD + (tid & 63)];
  const float hfq_reg = hfqg[(size_t)b * HD + tid];
  const float bp_reg = bp[tid];
  if (tid < 64) {
    float mu = enc0g[b * 128 + tid], lv = enc0g[b * 128 + 64 + tid];
    float s0 = softplusf_(lv + 0.5f) + 1e-8f;
    float z0 = mu + s0 * eps0[b * ZD + tid];
    zsh[tid] = z0;
    zsb[(b * KS) * ZD + tid] = bfc(z0);
    out_kl[(b * ZD + tid) * KS] = -logf(s0) + (s0 * s0 + mu * mu) * 0.5f - 0.5f;
  }
  __syncthreads();

  for (int t = 0; t < KS - 1; ++t) {
    // gates: q and p columns interleaved, pure register FMA
    float aq = hfq_reg, ap = bp_reg;
#pragma unroll
    for (int zp = 0; zp < 32; ++zp) {
      float z0v = zsh[2 * zp], z1v = zsh[2 * zp + 1];
      uint uq = wq[zp], up = wp[zp];
      aq += z0v * lof(uq) + z1v * hif(uq);
      ap += z0v * lof(up) + z1v * hif(up);
    }
    g[tid] = aq;
    gp[tid] = ap;
    __syncthreads();
    // LSTM (zero state): gate order i,f,g,o ; f unused
    if (tid < 128) {
      float cs = sigmoidf_(g[tid]) * tanhf(g[256 + tid]);
      hq[tid] = sigmoidf_(g[384 + tid]) * tanhf(cs);
    } else if (tid < 256) {
      int j = tid & 127;
      float cs = sigmoidf_(gp[j]) * tanhf(gp[256 + j]);
      hp[j] = sigmoidf_(gp[384 + j]) * tanhf(cs);
    }
    __syncthreads();
    // enc matvecs: 512 threads = {q,p} x {kc=0,1} x 128 cols
    {
      int s = tid & 255, jj = s & 127, kc = s >> 7;
      int mq_ = tid >> 8;  // 0=q, 1=p
      const float* h = mq_ ? hp : hq;
      const uint* W = WlL[mq_];
      float a = 0.f;
#pragma unroll
      for (int kp = 0; kp < 32; ++kp) {
        uint u = W[(kc * 32 + kp) * 128 + jj];
        a += h[kc * 64 + 2 * kp] * lof(u) + h[kc * 64 + 2 * kp + 1] * hif(u);
      }
      psum[tid] = a;
    }
    __syncthreads();
    // sample + KL (reduce psum inline)
    if (tid < 64) {
      float mq = psum[tid] + psum[128 + tid] + blinq[tid];
      float lq = psum[64 + tid] + psum[192 + tid] + blinq[64 + tid];
      float sq = softplusf_(lq + 0.5f) + 1e-8f;
      float zq = mq + sq * epsL[t * 64 + tid];
      float mp2 = psum[256 + tid] + psum[384 + tid] + blinp[tid];
      float lp = psum[320 + tid] + psum[448 + tid] + blinp[64 + tid];
      float sp_ = softplusf_(lp + 0.5f) + 1e-8f;
      float d = mq - mp2;
      out_kl[(b * ZD + tid) * KS + t + 1] =
          logf(sp_ / sq) + (sq * sq + d * d) / (2.f * sp_ * sp_) - 0.5f;
      zsb[(b * KS + t + 1) * ZD + tid] = bfc(zq);
      zsh[tid] = zq;
    }
    __syncthreads();
  }
}

// -------- W_dec transpose to bf16: WdT[col*64 + k] = bf16(Wd[k*DN + col]) --------
__global__ __launch_bounds__(256)
void wdt_kernel(const float* __restrict__ Wd, ushort* __restrict__ WdT) {
  const int c = blockIdx.x * 256 + threadIdx.x;
  uint packed[32];
#pragma unroll
  for (int k = 0; k < 32; ++k) {
    float a = Wd[(size_t)(2 * k) * DN + c];
    float b = Wd[(size_t)(2 * k + 1) * DN + c];
    packed[k] = pk2(a, b);
  }
  uint4* dst = (uint4*)&WdT[(size_t)c * 64];
#pragma unroll
  for (int i = 0; i < 8; ++i)
    dst[i] = make_uint4(packed[4 * i], packed[4 * i + 1], packed[4 * i + 2],
                        packed[4 * i + 3]);
}

// -------- Decoder: MFMA GEMM [2048 x 16384 x 64] + log-sigmoid + excl k-cumsum --------
__global__ __launch_bounds__(256)
void dec_kernel(const ushort* __restrict__ zsb, const ushort* __restrict__ WdT,
                const float* __restrict__ bd, float* __restrict__ out) {
  const int tid = threadIdx.x;
  const int lane = tid & 63;
  const int wave = tid >> 6;
  const int rr = lane & 15, gq = lane >> 4;
  const int mtile = blockIdx.y * 16;
  const int ncol0 = blockIdx.x * 256 + wave * 64;

  bf16x8 af[2];
#pragma unroll
  for (int ks2 = 0; ks2 < 2; ++ks2)
    af[ks2] = *(const bf16x8*)&zsb[(size_t)(mtile + rr) * 64 + ks2 * 32 + gq * 8];

  f32x4 acc[4];
#pragma unroll
  for (int nf = 0; nf < 4; ++nf) acc[nf] = (f32x4){0.f, 0.f, 0.f, 0.f};

#pragma unroll
  for (int ks2 = 0; ks2 < 2; ++ks2) {
#pragma unroll
    for (int nf = 0; nf < 4; ++nf) {
      bf16x8 bf = *(const bf16x8*)&WdT[(size_t)(ncol0 + nf * 16 + rr) * 64 +
                                       ks2 * 32 + gq * 8];
      acc[nf] = __builtin_amdgcn_mfma_f32_16x16x32_bf16(af[ks2], bf, acc[nf], 0, 0, 0);
    }
  }

  const int bb = (mtile >> 3) + (gq >> 1);
  const int khi = (gq & 1) * 4;
#pragma unroll
  for (int nf = 0; nf < 4; ++nf) {
    const int col = ncol0 + nf * 16 + rr;
    const float bde = bd[col];
    float run = 0.f;
    float ov[4];
#pragma unroll
    for (int i = 0; i < 4; ++i) {
      float dec = acc[nf][i] + bde;
      float spd = softplusf_(dec);
      ov[i] = run + (dec - spd);
      run -= spd;
    }
    float prev = __shfl_xor(run, 16, 64);
    float base = (gq & 1) ? prev : 0.f;
#pragma unroll
    for (int i = 0; i < 4; ++i) {
      const int k = khi + i;
      out[((size_t)k * NB + bb) * DN + col] = ov[i] + base;
    }
  }
}

extern "C" void kernel_launch(void* const* d_in, const int* in_sizes, int n_in,
                              void* d_out, int out_size, void* d_ws, size_t ws_size,
                              hipStream_t stream) {
  (void)in_sizes; (void)n_in; (void)out_size; (void)ws_size;
  const float* x     = (const float*)d_in[0];
  const float* eps0  = (const float*)d_in[2];
  const float* epsq  = (const float*)d_in[3];
  const float* Wstem = (const float*)d_in[5];
  const float* bstem = (const float*)d_in[6];
  const float* Wg    = (const float*)d_in[7];
  const float* bgp   = (const float*)d_in[8];
  const float* Wihq  = (const float*)d_in[9];
  const float* bq    = (const float*)d_in[10];
  const float* Wlinq = (const float*)d_in[11];
  const float* blinq = (const float*)d_in[12];
  const float* Wihp  = (const float*)d_in[13];
  const float* bp    = (const float*)d_in[14];
  const float* Wlinp = (const float*)d_in[15];
  const float* blinp = (const float*)d_in[16];
  const float* Wd    = (const float*)d_in[17];
  const float* bd    = (const float*)d_in[18];

  float* out    = (float*)d_out;
  float* outkl  = out + (size_t)KS * NB * DN;
  float* accbuf = (float*)d_ws;                        // 512 KB
  ushort* zsb   = (ushort*)(accbuf + NB * HD);         // 256 KB
  ushort* wdt   = zsb + (size_t)KS * NB * ZD;          // 2 MB
  ushort* wcombT = wdt + (size_t)DN * ZD;              // 640 KB
  float* hfqg   = (float*)(wcombT + 640 * 512);        // 512 KB
  float* enc0g  = hfqg + NB * HD;                      // 128 KB

  hipMemsetAsync(accbuf, 0, (size_t)NB * HD * sizeof(float), stream);
  wdt_kernel<<<DN / 256, 256, 0, stream>>>(Wd, wdt);
  wcombT_kernel<<<dim3(10, 8), 256, 0, stream>>>(Wihq, Wg, wcombT);
  stem_kernel<<<dim3(2, SPLITS), 512, 0, stream>>>(x, Wstem, accbuf);
  gemmA_kernel<<<dim3(10, 16), 256, 0, stream>>>(accbuf, bstem, wcombT, bq, bgp,
                                                 hfqg, enc0g);
  scan_kernel<<<NB, 512, 0, stream>>>(hfqg, enc0g, Wihq, Wihp, Wlinq, blinq,
                                      Wlinp, blinp, bp, eps0, epsq, zsb, outkl);
  dec_kernel<<<dim3(64, 128), 256, 0, stream>>>(zsb, wdt, bd, out);
}

// Round 5
// 239.931 us; speedup vs baseline: 1.5412x; 1.0311x over previous
//
#include <hip/hip_runtime.h>
#include <hip/hip_bf16.h>

#define ZD 64
#define HD 512
#define NB 256
#define KS 8
#define DIN 49152
#define DN 16384

typedef __attribute__((ext_vector_type(8))) short bf16x8;
typedef __attribute__((ext_vector_type(4))) float f32x4;

__device__ __forceinline__ ushort bfc(float x) {
  uint u = __float_as_uint(x);
  uint r = (u + 0x7FFFu + ((u >> 16) & 1u)) >> 16;
  return (ushort)r;
}
__device__ __forceinline__ uint pk2(float a, float b) {
  return (uint)bfc(a) | ((uint)bfc(b) << 16);
}
__device__ __forceinline__ float lof(uint u) { return __uint_as_float(u << 16); }
__device__ __forceinline__ float hif(uint u) { return __uint_as_float(u & 0xFFFF0000u); }
__device__ __forceinline__ float softplusf_(float x) {
  return fmaxf(x, 0.f) + log1pf(expf(-fabsf(x)));
}
__device__ __forceinline__ float sigmoidf_(float x) {
  return 1.f / (1.f + expf(-x));
}

// ---------------- Stem GEMM: acc[b][h] = sum_k x[b][k] * Wstem[k][h] ----------------
// BM=128, BN=256, split-K 128 (chunk 384), grid 4x128 = 512 blocks -> 2 blocks/CU.
#define SPLITS 128
#define KCH (DIN / SPLITS) /* 384 */
#define BKK 64

__global__ __launch_bounds__(512, 4)
void stem_kernel(const float* __restrict__ x, const float* __restrict__ W,
                 float* __restrict__ acc) {
  __shared__ ushort Ab[128][72];  // [row][k] bf16, 36 u32/row, granule-rotated
  __shared__ ushort Bt[256][72];  // transposed [n][k] bf16, 36 u32/row, linear
  const int nt = blockIdx.x >> 1, mt = blockIdx.x & 1;
  const int sp = blockIdx.y;
  const int m0 = mt * 128, n0 = nt * 256;
  const int tid  = threadIdx.x;
  const int lane = tid & 63;
  const int wave = tid >> 6;                 // 8 waves
  const int wm = wave >> 2, wn = wave & 3;   // wave tile: 64 rows x 64 cols

  f32x4 accr[4][4];
#pragma unroll
  for (int i = 0; i < 4; ++i)
#pragma unroll
    for (int j = 0; j < 4; ++j) accr[i][j] = (f32x4){0.f, 0.f, 0.f, 0.f};

  const int arow = tid >> 2, aq = tid & 3;         // A: 4 thr/row
  const int agr = ((aq + arow) & 3) * 8;           // rotated granule (u32 units)
  const int bnb = (tid >> 3) & 63;                 // B: n-subtile

#pragma unroll 1
  for (int it = 0; it < KCH / BKK; ++it) {
    const int k0 = sp * KCH + it * BKK;
    __syncthreads();
    {  // stage A: row arow, k-chunk aq*16..+16, store at rotated granule
      const float4* src = (const float4*)(x + (size_t)(m0 + arow) * DIN + k0 + aq * 16);
      uint2* dst = (uint2*)((uint*)&Ab[0][0] + arow * 36 + agr);
#pragma unroll
      for (int j = 0; j < 2; ++j) {
        float4 v0 = src[2 * j], v1 = src[2 * j + 1];
        dst[2 * j]     = make_uint2(pk2(v0.x, v0.y), pk2(v0.z, v0.w));
        dst[2 * j + 1] = make_uint2(pk2(v1.x, v1.y), pk2(v1.z, v1.w));
      }
    }
    {  // stage B: 4x4 register transpose, 2 rounds; Bt row = col n, linear k
#pragma unroll
      for (int r2 = 0; r2 < 2; ++r2) {
        const int kb = (tid & 7) + r2 * 8;
        float4 v[4];
#pragma unroll
        for (int i = 0; i < 4; ++i)
          v[i] = *(const float4*)(W + (size_t)(k0 + kb * 4 + i) * HD + n0 + bnb * 4);
#pragma unroll
        for (int c = 0; c < 4; ++c) {
          const float* p0 = (const float*)&v[0];
          const float* p1 = (const float*)&v[1];
          const float* p2 = (const float*)&v[2];
          const float* p3 = (const float*)&v[3];
          *(uint2*)((uint*)&Bt[0][0] + (bnb * 4 + c) * 36 + kb * 2) =
              make_uint2(pk2(p0[c], p1[c]), pk2(p2[c], p3[c]));
        }
      }
    }
    __syncthreads();
    const int rr = lane & 15, gq = lane >> 4;
#pragma unroll
    for (int ks = 0; ks < 2; ++ks) {
      bf16x8 af[4], bfr[4];
#pragma unroll
      for (int mf = 0; mf < 4; ++mf) {
        const int row = wm * 64 + mf * 16 + rr;
        const int q = 2 * ks + (gq >> 1);           // k-chunk index (granule)
        const int off = row * 36 + (((q + row) & 3) * 8) + (gq & 1) * 4;
        af[mf] = *(const bf16x8*)((const uint*)&Ab[0][0] + off);
      }
#pragma unroll
      for (int nf = 0; nf < 4; ++nf) {
        const int rown = wn * 64 + nf * 16 + rr;
        bfr[nf] = *(const bf16x8*)((const uint*)&Bt[0][0] + rown * 36 + ks * 16 + gq * 4);
      }
#pragma unroll
      for (int mf = 0; mf < 4; ++mf)
#pragma unroll
        for (int nf = 0; nf < 4; ++nf)
          accr[mf][nf] = __builtin_amdgcn_mfma_f32_16x16x32_bf16(
              af[mf], bfr[nf], accr[mf][nf], 0, 0, 0);
    }
  }
  // C/D layout: col = lane&15, row = 4*(lane>>4) + i
  const int ccol = lane & 15, crow = (lane >> 4) * 4;
#pragma unroll
  for (int mf = 0; mf < 4; ++mf) {
#pragma unroll
    for (int nf = 0; nf < 4; ++nf) {
      const int col = n0 + wn * 64 + nf * 16 + ccol;
      const int row = m0 + wm * 64 + mf * 16 + crow;
#pragma unroll
      for (int i = 0; i < 4; ++i)
        atomicAdd(&acc[(row + i) * HD + col], accr[mf][nf][i]);
    }
  }
}

// ---- WcombT: bf16 [640 cols][512 k] of B = [Wihq[:512] | Wg] (64x64 tile transpose) ----
__global__ __launch_bounds__(256)
void wcombT_kernel(const float* __restrict__ Wihq, const float* __restrict__ Wg,
                   ushort* __restrict__ WcT) {
  __shared__ float T[64][68];
  const int bx = blockIdx.x;  // col tile 0..9
  const int by = blockIdx.y;  // k tile 0..7
  const int t = threadIdx.x;
  const int ct = bx * 64, kt = by * 64;
  {
    const int rl = t >> 2, cq = (t & 3) * 16;
    const float* src = (bx < 8) ? &Wihq[(size_t)(kt + rl) * 512 + ct + cq]
                                : &Wg[(size_t)(kt + rl) * 128 + (ct - 512) + cq];
#pragma unroll
    for (int i = 0; i < 4; ++i) {
      float4 v = *(const float4*)(src + 4 * i);
      T[rl][cq + 4 * i + 0] = v.x;
      T[rl][cq + 4 * i + 1] = v.y;
      T[rl][cq + 4 * i + 2] = v.z;
      T[rl][cq + 4 * i + 3] = v.w;
    }
  }
  __syncthreads();
  {
    const int cl = t >> 2, kq = (t & 3) * 16;
    uint* dst = (uint*)WcT;
#pragma unroll
    for (int i = 0; i < 8; ++i) {
      uint u = pk2(T[kq + 2 * i][cl], T[kq + 2 * i + 1][cl]);
      dst[(((size_t)(ct + cl)) * 512 + kt + kq + 2 * i) >> 1] = u;
    }
  }
}

// ---- gemmA: hf = relu(acc+bstem); hfqg = hf@Wihq[:512]+bq ; enc0g = hf@Wg+bg ----
__global__ __launch_bounds__(256)
void gemmA_kernel(const float* __restrict__ acc, const float* __restrict__ bstem,
                  const ushort* __restrict__ WcT, const float* __restrict__ bq,
                  const float* __restrict__ bg, float* __restrict__ hfqg,
                  float* __restrict__ enc0g) {
  const int tid = threadIdx.x;
  const int lane = tid & 63;
  const int wave = tid >> 6;
  const int rr = lane & 15, gq = lane >> 4;
  const int mtile = blockIdx.y * 16;
  const int ncol = blockIdx.x * 64 + wave * 16;
  const int row = mtile + rr;

  f32x4 a4 = (f32x4){0.f, 0.f, 0.f, 0.f};
#pragma unroll
  for (int ks2 = 0; ks2 < 16; ++ks2) {
    const int k0 = ks2 * 32 + gq * 8;
    float4 x0 = *(const float4*)&acc[(size_t)row * HD + k0];
    float4 x1 = *(const float4*)&acc[(size_t)row * HD + k0 + 4];
    float4 b0 = *(const float4*)&bstem[k0];
    float4 b1 = *(const float4*)&bstem[k0 + 4];
    bf16x8 af;
    af[0] = (short)bfc(fmaxf(x0.x + b0.x, 0.f));
    af[1] = (short)bfc(fmaxf(x0.y + b0.y, 0.f));
    af[2] = (short)bfc(fmaxf(x0.z + b0.z, 0.f));
    af[3] = (short)bfc(fmaxf(x0.w + b0.w, 0.f));
    af[4] = (short)bfc(fmaxf(x1.x + b1.x, 0.f));
    af[5] = (short)bfc(fmaxf(x1.y + b1.y, 0.f));
    af[6] = (short)bfc(fmaxf(x1.z + b1.z, 0.f));
    af[7] = (short)bfc(fmaxf(x1.w + b1.w, 0.f));
    bf16x8 bf = *(const bf16x8*)&WcT[(size_t)(ncol + rr) * 512 + k0];
    a4 = __builtin_amdgcn_mfma_f32_16x16x32_bf16(af, bf, a4, 0, 0, 0);
  }
  const int col = ncol + rr;
  if (col < 512) {
    const float bb = bq[col];
#pragma unroll
    for (int i = 0; i < 4; ++i)
      hfqg[(size_t)(mtile + 4 * gq + i) * HD + col] = a4[i] + bb;
  } else {
    const float bb = bg[col - 512];
#pragma unroll
    for (int i = 0; i < 4; ++i)
      enc0g[(size_t)(mtile + 4 * gq + i) * 128 + (col - 512)] = a4[i] + bb;
  }
}

// ---------------- Recurrent scan: one block (512 thr) per batch row ----------------
__global__ __launch_bounds__(512, 2)
void scan_kernel(const float* __restrict__ hfqg, const float* __restrict__ enc0g,
                 const float* __restrict__ Wihq, const float* __restrict__ Wihp,
                 const float* __restrict__ Wlinq, const float* __restrict__ blinq,
                 const float* __restrict__ Wlinp, const float* __restrict__ blinp,
                 const float* __restrict__ bp,
                 const float* __restrict__ eps0, const float* __restrict__ epsq,
                 ushort* __restrict__ zsb, float* __restrict__ out_kl) {
  const int b = blockIdx.x, tid = threadIdx.x;
  __shared__ uint WlL[2][64 * 128];
  __shared__ float g[512], gp[512];
  __shared__ float hq[128], hp[128];
  __shared__ float psum[512];
  __shared__ float zsh[64];
  __shared__ float epsL[448];

  uint wq[32], wp[32];
#pragma unroll
  for (int zp = 0; zp < 32; ++zp) {
    wq[zp] = pk2(Wihq[(size_t)(HD + 2 * zp) * HD + tid],
                 Wihq[(size_t)(HD + 2 * zp + 1) * HD + tid]);
    wp[zp] = pk2(Wihp[(size_t)(2 * zp) * HD + tid],
                 Wihp[(size_t)(2 * zp + 1) * HD + tid]);
  }
#pragma unroll
  for (int i = 0; i < 16; ++i) {
    int idx = i * 512 + tid;
    int kp2 = idx >> 7, jj = idx & 127;
    WlL[0][idx] = pk2(Wlinq[(2 * kp2) * 128 + jj], Wlinq[(2 * kp2 + 1) * 128 + jj]);
    WlL[1][idx] = pk2(Wlinp[(2 * kp2) * 128 + jj], Wlinp[(2 * kp2 + 1) * 128 + jj]);
  }
  if (tid < 448) epsL[tid] = epsq[(size_t)((tid >> 6) * NB + b) * ZD + (tid & 63)];
  const float hfq_reg = hfqg[(size_t)b * HD + tid];
  const float bp_reg = bp[tid];
  if (tid < 64) {
    float mu = enc0g[b * 128 + tid], lv = enc0g[b * 128 + 64 + tid];
    float s0 = softplusf_(lv + 0.5f) + 1e-8f;
    float z0 = mu + s0 * eps0[b * ZD + tid];
    zsh[tid] = z0;
    zsb[(b * KS) * ZD + tid] = bfc(z0);
    out_kl[(b * ZD + tid) * KS] = -logf(s0) + (s0 * s0 + mu * mu) * 0.5f - 0.5f;
  }
  __syncthreads();

  for (int t = 0; t < KS - 1; ++t) {
    float aq = hfq_reg, ap = bp_reg;
#pragma unroll
    for (int zp = 0; zp < 32; ++zp) {
      float z0v = zsh[2 * zp], z1v = zsh[2 * zp + 1];
      uint uq = wq[zp], up = wp[zp];
      aq += z0v * lof(uq) + z1v * hif(uq);
      ap += z0v * lof(up) + z1v * hif(up);
    }
    g[tid] = aq;
    gp[tid] = ap;
    __syncthreads();
    if (tid < 128) {
      float cs = sigmoidf_(g[tid]) * tanhf(g[256 + tid]);
      hq[tid] = sigmoidf_(g[384 + tid]) * tanhf(cs);
    } else if (tid < 256) {
      int j = tid & 127;
      float cs = sigmoidf_(gp[j]) * tanhf(gp[256 + j]);
      hp[j] = sigmoidf_(gp[384 + j]) * tanhf(cs);
    }
    __syncthreads();
    {
      int s = tid & 255, jj = s & 127, kc = s >> 7;
      int mq_ = tid >> 8;
      const float* h = mq_ ? hp : hq;
      const uint* W = WlL[mq_];
      float a = 0.f;
#pragma unroll
      for (int kp = 0; kp < 32; ++kp) {
        uint u = W[(kc * 32 + kp) * 128 + jj];
        a += h[kc * 64 + 2 * kp] * lof(u) + h[kc * 64 + 2 * kp + 1] * hif(u);
      }
      psum[tid] = a;
    }
    __syncthreads();
    if (tid < 64) {
      float mq = psum[tid] + psum[128 + tid] + blinq[tid];
      float lq = psum[64 + tid] + psum[192 + tid] + blinq[64 + tid];
      float sq = softplusf_(lq + 0.5f) + 1e-8f;
      float zq = mq + sq * epsL[t * 64 + tid];
      float mp2 = psum[256 + tid] + psum[384 + tid] + blinp[tid];
      float lp = psum[320 + tid] + psum[448 + tid] + blinp[64 + tid];
      float sp_ = softplusf_(lp + 0.5f) + 1e-8f;
      float d = mq - mp2;
      out_kl[(b * ZD + tid) * KS + t + 1] =
          logf(sp_ / sq) + (sq * sq + d * d) / (2.f * sp_ * sp_) - 0.5f;
      zsb[(b * KS + t + 1) * ZD + tid] = bfc(zq);
      zsh[tid] = zq;
    }
    __syncthreads();
  }
}

// -------- W_dec transpose to bf16: WdT[col*64 + k] = bf16(Wd[k*DN + col]) --------
__global__ __launch_bounds__(256)
void wdt_kernel(const float* __restrict__ Wd, ushort* __restrict__ WdT) {
  const int c = blockIdx.x * 256 + threadIdx.x;
  uint packed[32];
#pragma unroll
  for (int k = 0; k < 32; ++k) {
    float a = Wd[(size_t)(2 * k) * DN + c];
    float b = Wd[(size_t)(2 * k + 1) * DN + c];
    packed[k] = pk2(a, b);
  }
  uint4* dst = (uint4*)&WdT[(size_t)c * 64];
#pragma unroll
  for (int i = 0; i < 8; ++i)
    dst[i] = make_uint4(packed[4 * i], packed[4 * i + 1], packed[4 * i + 2],
                        packed[4 * i + 3]);
}

// -------- Decoder: MFMA GEMM [2048 x 16384 x 64] + log-sigmoid + excl k-cumsum --------
__global__ __launch_bounds__(256)
void dec_kernel(const ushort* __restrict__ zsb, const ushort* __restrict__ WdT,
                const float* __restrict__ bd, float* __restrict__ out) {
  const int tid = threadIdx.x;
  const int lane = tid & 63;
  const int wave = tid >> 6;
  const int rr = lane & 15, gq = lane >> 4;
  const int mtile = blockIdx.y * 16;
  const int ncol0 = blockIdx.x * 256 + wave * 64;

  bf16x8 af[2];
#pragma unroll
  for (int ks2 = 0; ks2 < 2; ++ks2)
    af[ks2] = *(const bf16x8*)&zsb[(size_t)(mtile + rr) * 64 + ks2 * 32 + gq * 8];

  f32x4 acc[4];
#pragma unroll
  for (int nf = 0; nf < 4; ++nf) acc[nf] = (f32x4){0.f, 0.f, 0.f, 0.f};

#pragma unroll
  for (int ks2 = 0; ks2 < 2; ++ks2) {
#pragma unroll
    for (int nf = 0; nf < 4; ++nf) {
      bf16x8 bf = *(const bf16x8*)&WdT[(size_t)(ncol0 + nf * 16 + rr) * 64 +
                                       ks2 * 32 + gq * 8];
      acc[nf] = __builtin_amdgcn_mfma_f32_16x16x32_bf16(af[ks2], bf, acc[nf], 0, 0, 0);
    }
  }

  const int bb = (mtile >> 3) + (gq >> 1);
  const int khi = (gq & 1) * 4;
#pragma unroll
  for (int nf = 0; nf < 4; ++nf) {
    const int col = ncol0 + nf * 16 + rr;
    const float bde = bd[col];
    float run = 0.f;
    float ov[4];
#pragma unroll
    for (int i = 0; i < 4; ++i) {
      float dec = acc[nf][i] + bde;
      float spd = softplusf_(dec);
      ov[i] = run + (dec - spd);
      run -= spd;
    }
    float prev = __shfl_xor(run, 16, 64);
    float base = (gq & 1) ? prev : 0.f;
#pragma unroll
    for (int i = 0; i < 4; ++i) {
      const int k = khi + i;
      out[((size_t)k * NB + bb) * DN + col] = ov[i] + base;
    }
  }
}

extern "C" void kernel_launch(void* const* d_in, const int* in_sizes, int n_in,
                              void* d_out, int out_size, void* d_ws, size_t ws_size,
                              hipStream_t stream) {
  (void)in_sizes; (void)n_in; (void)out_size; (void)ws_size;
  const float* x     = (const float*)d_in[0];
  const float* eps0  = (const float*)d_in[2];
  const float* epsq  = (const float*)d_in[3];
  const float* Wstem = (const float*)d_in[5];
  const float* bstem = (const float*)d_in[6];
  const float* Wg    = (const float*)d_in[7];
  const float* bgp   = (const float*)d_in[8];
  const float* Wihq  = (const float*)d_in[9];
  const float* bq    = (const float*)d_in[10];
  const float* Wlinq = (const float*)d_in[11];
  const float* blinq = (const float*)d_in[12];
  const float* Wihp  = (const float*)d_in[13];
  const float* bp    = (const float*)d_in[14];
  const float* Wlinp = (const float*)d_in[15];
  const float* blinp = (const float*)d_in[16];
  const float* Wd    = (const float*)d_in[17];
  const float* bd    = (const float*)d_in[18];

  float* out    = (float*)d_out;
  float* outkl  = out + (size_t)KS * NB * DN;
  float* accbuf = (float*)d_ws;
  ushort* zsb   = (ushort*)(accbuf + NB * HD);
  ushort* wdt   = zsb + (size_t)KS * NB * ZD;
  ushort* wcombT = wdt + (size_t)DN * ZD;
  float* hfqg   = (float*)(wcombT + 640 * 512);
  float* enc0g  = hfqg + NB * HD;

  hipMemsetAsync(accbuf, 0, (size_t)NB * HD * sizeof(float), stream);
  wdt_kernel<<<DN / 256, 256, 0, stream>>>(Wd, wdt);
  wcombT_kernel<<<dim3(10, 8), 256, 0, stream>>>(Wihq, Wg, wcombT);
  stem_kernel<<<dim3(4, SPLITS), 512, 0, stream>>>(x, Wstem, accbuf);
  gemmA_kernel<<<dim3(10, 16), 256, 0, stream>>>(accbuf, bstem, wcombT, bq, bgp,
                                                 hfqg, enc0g);
  scan_kernel<<<NB, 512, 0, stream>>>(hfqg, enc0g, Wihq, Wihp, Wlinq, blinq,
                                      Wlinp, blinp, bp, eps0, epsq, zsb, outkl);
  dec_kernel<<<dim3(64, 128), 256, 0, stream>>>(zsb, wdt, bd, out);
}

// Round 6
// 162.969 us; speedup vs baseline: 2.2691x; 1.4722x over previous
//
#include <hip/hip_runtime.h>
#include <hip/hip_bf16.h>

#define ZD 64
#define HD 512
#define NB 256
#define KS 8
#define DIN 49152
#define DN 16384

typedef __attribute__((ext_vector_type(8))) short bf16x8;
typedef __attribute__((ext_vector_type(4))) float f32x4;

__device__ __forceinline__ ushort bfc(float x) {
  uint u = __float_as_uint(x);
  uint r = (u + 0x7FFFu + ((u >> 16) & 1u)) >> 16;
  return (ushort)r;
}
__device__ __forceinline__ uint pk2(float a, float b) {
  return (uint)bfc(a) | ((uint)bfc(b) << 16);
}
__device__ __forceinline__ float lof(uint u) { return __uint_as_float(u << 16); }
__device__ __forceinline__ float hif(uint u) { return __uint_as_float(u & 0xFFFF0000u); }
__device__ __forceinline__ float softplusf_(float x) {
  return fmaxf(x, 0.f) + log1pf(expf(-fabsf(x)));
}
__device__ __forceinline__ float softplus_fast(float x) {
  // |err| ~1e-6 absolute; output threshold is 0.3575
  float e = __expf(-fabsf(x));
  return fmaxf(x, 0.f) + __logf(1.f + e);
}
__device__ __forceinline__ float sigmoidf_(float x) {
  return 1.f / (1.f + expf(-x));
}

// ---------------- Stem GEMM stage 1: partials[sp][b][h], NO atomics ----------------
// BM=128, BN=128, SPLITS=64 (K-chunk 768), grid (8 tiles, 64 splits) = 512 blocks.
#define SPLITS 64
#define KCH (DIN / SPLITS) /* 768 */
#define BKK 64

__global__ __launch_bounds__(256)
void stem_kernel(const float* __restrict__ x, const float* __restrict__ W,
                 float* __restrict__ part) {
  __shared__ ushort Ab[128][72];  // [row][k] bf16, 36 u32/row, granule-rotated
  __shared__ ushort Bt[128][72];  // transposed [n][k] bf16, granule-rotated
  const int mt = blockIdx.x >> 2, nt = blockIdx.x & 3;  // 2 x 4 tiles
  const int sp = blockIdx.y;                            // 0..63
  const int m0 = mt * 128, n0 = nt * 128;
  const int tid  = threadIdx.x;
  const int lane = tid & 63;
  const int wave = tid >> 6;                 // 4 waves
  const int wm = wave >> 1, wn = wave & 1;   // wave tile: 64 x 64

  f32x4 accr[4][4];
#pragma unroll
  for (int i = 0; i < 4; ++i)
#pragma unroll
    for (int j = 0; j < 4; ++j) accr[i][j] = (f32x4){0.f, 0.f, 0.f, 0.f};

  const int arow = tid >> 1, aq = tid & 1;   // A: 2 thr/row, 32 f32 each
  const int bnb = tid & 31, kb = tid >> 5;   // B: col-group, 8-row k-group

#pragma unroll 1
  for (int it = 0; it < KCH / BKK; ++it) {
    const int k0 = sp * KCH + it * BKK;
    __syncthreads();
    {  // stage A: x[(m0+arow)][k0+aq*32 .. +32] -> rotated granules
      const float4* src = (const float4*)(x + (size_t)(m0 + arow) * DIN + k0 + aq * 32);
      uint* base = (uint*)&Ab[0][0] + arow * 36;
#pragma unroll
      for (int j = 0; j < 8; ++j) {
        float4 v = src[j];
        const int off = ((aq * 2 + (j >> 2) + arow) & 3) * 8 + (j & 3) * 2;
        *(uint2*)(base + off) = make_uint2(pk2(v.x, v.y), pk2(v.z, v.w));
      }
    }
    {  // stage B: rows k0+kb*8..+8, cols n0+bnb*4..+4; 8x4 register transpose
      float4 v[8];
#pragma unroll
      for (int i = 0; i < 8; ++i)
        v[i] = *(const float4*)(W + (size_t)(k0 + kb * 8 + i) * HD + n0 + bnb * 4);
#pragma unroll
      for (int c = 0; c < 4; ++c) {
        const int row = bnb * 4 + c;
        const float* p = (const float*)v;
        const int off = row * 36 + (((kb >> 1) + row) & 3) * 8 + (kb & 1) * 4;
        *(uint4*)((uint*)&Bt[0][0] + off) =
            make_uint4(pk2(p[0 * 4 + c], p[1 * 4 + c]), pk2(p[2 * 4 + c], p[3 * 4 + c]),
                       pk2(p[4 * 4 + c], p[5 * 4 + c]), pk2(p[6 * 4 + c], p[7 * 4 + c]));
      }
    }
    __syncthreads();
    const int rr = lane & 15, gq = lane >> 4;
#pragma unroll
    for (int ks = 0; ks < 2; ++ks) {
      const int q = 2 * ks + (gq >> 1);
      const int sub = (gq & 1) * 4;
      bf16x8 af[4], bfr[4];
#pragma unroll
      for (int mf = 0; mf < 4; ++mf) {
        const int row = wm * 64 + mf * 16 + rr;
        af[mf] = *(const bf16x8*)((const uint*)&Ab[0][0] + row * 36 +
                                  ((q + row) & 3) * 8 + sub);
      }
#pragma unroll
      for (int nf = 0; nf < 4; ++nf) {
        const int rown = wn * 64 + nf * 16 + rr;
        bfr[nf] = *(const bf16x8*)((const uint*)&Bt[0][0] + rown * 36 +
                                   ((q + rown) & 3) * 8 + sub);
      }
#pragma unroll
      for (int mf = 0; mf < 4; ++mf)
#pragma unroll
        for (int nf = 0; nf < 4; ++nf)
          accr[mf][nf] = __builtin_amdgcn_mfma_f32_16x16x32_bf16(
              af[mf], bfr[nf], accr[mf][nf], 0, 0, 0);
    }
  }
  // C/D layout: col = lane&15, row = 4*(lane>>4)+i ; plain coalesced stores
  const int ccol = lane & 15, crow = (lane >> 4) * 4;
  float* base = part + (size_t)sp * (NB * HD);
#pragma unroll
  for (int mf = 0; mf < 4; ++mf) {
#pragma unroll
    for (int nf = 0; nf < 4; ++nf) {
      const int col = n0 + wn * 64 + nf * 16 + ccol;
      const int row = m0 + wm * 64 + mf * 16 + crow;
#pragma unroll
      for (int i = 0; i < 4; ++i)
        base[(size_t)(row + i) * HD + col] = accr[mf][nf][i];
    }
  }
}

// ---------------- Stem stage 2: acc = sum over 64 splits ----------------
__global__ __launch_bounds__(256)
void reduce_kernel(const float* __restrict__ part, float* __restrict__ acc) {
  const int idx = blockIdx.x * 256 + threadIdx.x;  // float4 index, 32768 total
  const float4* p = (const float4*)part;
  float4 s = p[idx];
#pragma unroll 8
  for (int sp = 1; sp < SPLITS; ++sp) {
    float4 v = p[(size_t)sp * (NB * HD / 4) + idx];
    s.x += v.x; s.y += v.y; s.z += v.z; s.w += v.w;
  }
  ((float4*)acc)[idx] = s;
}

// ---- WcombT: bf16 [640 cols][512 k] of B = [Wihq[:512] | Wg] ----
__global__ __launch_bounds__(256)
void wcombT_kernel(const float* __restrict__ Wihq, const float* __restrict__ Wg,
                   ushort* __restrict__ WcT) {
  __shared__ float T[64][68];
  const int bx = blockIdx.x;
  const int by = blockIdx.y;
  const int t = threadIdx.x;
  const int ct = bx * 64, kt = by * 64;
  {
    const int rl = t >> 2, cq = (t & 3) * 16;
    const float* src = (bx < 8) ? &Wihq[(size_t)(kt + rl) * 512 + ct + cq]
                                : &Wg[(size_t)(kt + rl) * 128 + (ct - 512) + cq];
#pragma unroll
    for (int i = 0; i < 4; ++i) {
      float4 v = *(const float4*)(src + 4 * i);
      T[rl][cq + 4 * i + 0] = v.x;
      T[rl][cq + 4 * i + 1] = v.y;
      T[rl][cq + 4 * i + 2] = v.z;
      T[rl][cq + 4 * i + 3] = v.w;
    }
  }
  __syncthreads();
  {
    const int cl = t >> 2, kq = (t & 3) * 16;
    uint* dst = (uint*)WcT;
#pragma unroll
    for (int i = 0; i < 8; ++i) {
      uint u = pk2(T[kq + 2 * i][cl], T[kq + 2 * i + 1][cl]);
      dst[(((size_t)(ct + cl)) * 512 + kt + kq + 2 * i) >> 1] = u;
    }
  }
}

// ---- gemmA: hf = relu(acc+bstem); hfqg = hf@Wihq[:512]+bq ; enc0g = hf@Wg+bg ----
__global__ __launch_bounds__(256)
void gemmA_kernel(const float* __restrict__ acc, const float* __restrict__ bstem,
                  const ushort* __restrict__ WcT, const float* __restrict__ bq,
                  const float* __restrict__ bg, float* __restrict__ hfqg,
                  float* __restrict__ enc0g) {
  const int tid = threadIdx.x;
  const int lane = tid & 63;
  const int wave = tid >> 6;
  const int rr = lane & 15, gq = lane >> 4;
  const int mtile = blockIdx.y * 16;
  const int ncol = blockIdx.x * 64 + wave * 16;
  const int row = mtile + rr;

  f32x4 a4 = (f32x4){0.f, 0.f, 0.f, 0.f};
#pragma unroll
  for (int ks2 = 0; ks2 < 16; ++ks2) {
    const int k0 = ks2 * 32 + gq * 8;
    float4 x0 = *(const float4*)&acc[(size_t)row * HD + k0];
    float4 x1 = *(const float4*)&acc[(size_t)row * HD + k0 + 4];
    float4 b0 = *(const float4*)&bstem[k0];
    float4 b1 = *(const float4*)&bstem[k0 + 4];
    bf16x8 af;
    af[0] = (short)bfc(fmaxf(x0.x + b0.x, 0.f));
    af[1] = (short)bfc(fmaxf(x0.y + b0.y, 0.f));
    af[2] = (short)bfc(fmaxf(x0.z + b0.z, 0.f));
    af[3] = (short)bfc(fmaxf(x0.w + b0.w, 0.f));
    af[4] = (short)bfc(fmaxf(x1.x + b1.x, 0.f));
    af[5] = (short)bfc(fmaxf(x1.y + b1.y, 0.f));
    af[6] = (short)bfc(fmaxf(x1.z + b1.z, 0.f));
    af[7] = (short)bfc(fmaxf(x1.w + b1.w, 0.f));
    bf16x8 bf = *(const bf16x8*)&WcT[(size_t)(ncol + rr) * 512 + k0];
    a4 = __builtin_amdgcn_mfma_f32_16x16x32_bf16(af, bf, a4, 0, 0, 0);
  }
  const int col = ncol + rr;
  if (col < 512) {
    const float bb = bq[col];
#pragma unroll
    for (int i = 0; i < 4; ++i)
      hfqg[(size_t)(mtile + 4 * gq + i) * HD + col] = a4[i] + bb;
  } else {
    const float bb = bg[col - 512];
#pragma unroll
    for (int i = 0; i < 4; ++i)
      enc0g[(size_t)(mtile + 4 * gq + i) * 128 + (col - 512)] = a4[i] + bb;
  }
}

// ---------------- Recurrent scan: one block (512 thr) per batch row ----------------
__global__ __launch_bounds__(512, 2)
void scan_kernel(const float* __restrict__ hfqg, const float* __restrict__ enc0g,
                 const float* __restrict__ Wihq, const float* __restrict__ Wihp,
                 const float* __restrict__ Wlinq, const float* __restrict__ blinq,
                 const float* __restrict__ Wlinp, const float* __restrict__ blinp,
                 const float* __restrict__ bp,
                 const float* __restrict__ eps0, const float* __restrict__ epsq,
                 ushort* __restrict__ zsb, float* __restrict__ out_kl) {
  const int b = blockIdx.x, tid = threadIdx.x;
  __shared__ uint WlL[2][64 * 128];
  __shared__ float g[512], gp[512];
  __shared__ float hq[128], hp[128];
  __shared__ float psum[512];
  __shared__ float zsh[64];
  __shared__ float epsL[448];

  uint wq[32], wp[32];
#pragma unroll
  for (int zp = 0; zp < 32; ++zp) {
    wq[zp] = pk2(Wihq[(size_t)(HD + 2 * zp) * HD + tid],
                 Wihq[(size_t)(HD + 2 * zp + 1) * HD + tid]);
    wp[zp] = pk2(Wihp[(size_t)(2 * zp) * HD + tid],
                 Wihp[(size_t)(2 * zp + 1) * HD + tid]);
  }
#pragma unroll
  for (int i = 0; i < 16; ++i) {
    int idx = i * 512 + tid;
    int kp2 = idx >> 7, jj = idx & 127;
    WlL[0][idx] = pk2(Wlinq[(2 * kp2) * 128 + jj], Wlinq[(2 * kp2 + 1) * 128 + jj]);
    WlL[1][idx] = pk2(Wlinp[(2 * kp2) * 128 + jj], Wlinp[(2 * kp2 + 1) * 128 + jj]);
  }
  if (tid < 448) epsL[tid] = epsq[(size_t)((tid >> 6) * NB + b) * ZD + (tid & 63)];
  const float hfq_reg = hfqg[(size_t)b * HD + tid];
  const float bp_reg = bp[tid];
  if (tid < 64) {
    float mu = enc0g[b * 128 + tid], lv = enc0g[b * 128 + 64 + tid];
    float s0 = softplusf_(lv + 0.5f) + 1e-8f;
    float z0 = mu + s0 * eps0[b * ZD + tid];
    zsh[tid] = z0;
    zsb[(b * KS) * ZD + tid] = bfc(z0);
    out_kl[(b * ZD + tid) * KS] = -logf(s0) + (s0 * s0 + mu * mu) * 0.5f - 0.5f;
  }
  __syncthreads();

  for (int t = 0; t < KS - 1; ++t) {
    float aq = hfq_reg, ap = bp_reg;
#pragma unroll
    for (int zp = 0; zp < 32; ++zp) {
      float z0v = zsh[2 * zp], z1v = zsh[2 * zp + 1];
      uint uq = wq[zp], up = wp[zp];
      aq += z0v * lof(uq) + z1v * hif(uq);
      ap += z0v * lof(up) + z1v * hif(up);
    }
    g[tid] = aq;
    gp[tid] = ap;
    __syncthreads();
    if (tid < 128) {
      float cs = sigmoidf_(g[tid]) * tanhf(g[256 + tid]);
      hq[tid] = sigmoidf_(g[384 + tid]) * tanhf(cs);
    } else if (tid < 256) {
      int j = tid & 127;
      float cs = sigmoidf_(gp[j]) * tanhf(gp[256 + j]);
      hp[j] = sigmoidf_(gp[384 + j]) * tanhf(cs);
    }
    __syncthreads();
    {
      int s = tid & 255, jj = s & 127, kc = s >> 7;
      int mq_ = tid >> 8;
      const float* h = mq_ ? hp : hq;
      const uint* W = WlL[mq_];
      float a = 0.f;
#pragma unroll
      for (int kp = 0; kp < 32; ++kp) {
        uint u = W[(kc * 32 + kp) * 128 + jj];
        a += h[kc * 64 + 2 * kp] * lof(u) + h[kc * 64 + 2 * kp + 1] * hif(u);
      }
      psum[tid] = a;
    }
    __syncthreads();
    if (tid < 64) {
      float mq = psum[tid] + psum[128 + tid] + blinq[tid];
      float lq = psum[64 + tid] + psum[192 + tid] + blinq[64 + tid];
      float sq = softplusf_(lq + 0.5f) + 1e-8f;
      float zq = mq + sq * epsL[t * 64 + tid];
      float mp2 = psum[256 + tid] + psum[384 + tid] + blinp[tid];
      float lp = psum[320 + tid] + psum[448 + tid] + blinp[64 + tid];
      float sp_ = softplusf_(lp + 0.5f) + 1e-8f;
      float d = mq - mp2;
      out_kl[(b * ZD + tid) * KS + t + 1] =
          logf(sp_ / sq) + (sq * sq + d * d) / (2.f * sp_ * sp_) - 0.5f;
      zsb[(b * KS + t + 1) * ZD + tid] = bfc(zq);
      zsh[tid] = zq;
    }
    __syncthreads();
  }
}

// -------- W_dec transpose to bf16 --------
__global__ __launch_bounds__(256)
void wdt_kernel(const float* __restrict__ Wd, ushort* __restrict__ WdT) {
  const int c = blockIdx.x * 256 + threadIdx.x;
  uint packed[32];
#pragma unroll
  for (int k = 0; k < 32; ++k) {
    float a = Wd[(size_t)(2 * k) * DN + c];
    float b = Wd[(size_t)(2 * k + 1) * DN + c];
    packed[k] = pk2(a, b);
  }
  uint4* dst = (uint4*)&WdT[(size_t)c * 64];
#pragma unroll
  for (int i = 0; i < 8; ++i)
    dst[i] = make_uint4(packed[4 * i], packed[4 * i + 1], packed[4 * i + 2],
                        packed[4 * i + 3]);
}

// -------- Decoder: MFMA + log-sigmoid + excl k-cumsum. 2 m-tiles/block, ILP-hoisted --------
__global__ __launch_bounds__(256)
void dec_kernel(const ushort* __restrict__ zsb, const ushort* __restrict__ WdT,
                const float* __restrict__ bd, float* __restrict__ out) {
  const int tid = threadIdx.x;
  const int lane = tid & 63;
  const int wave = tid >> 6;
  const int rr = lane & 15, gq = lane >> 4;
  const int mtile0 = blockIdx.y * 32;              // 2048/32 = 64
  const int ncol0 = blockIdx.x * 256 + wave * 64;  // 16384/256 = 64

  // hoist ALL independent loads before any MFMA (force ILP / in-flight loads)
  bf16x8 bfr[2][4];
#pragma unroll
  for (int ks2 = 0; ks2 < 2; ++ks2)
#pragma unroll
    for (int nf = 0; nf < 4; ++nf)
      bfr[ks2][nf] = *(const bf16x8*)&WdT[(size_t)(ncol0 + nf * 16 + rr) * 64 +
                                          ks2 * 32 + gq * 8];
  bf16x8 af[2][2];
#pragma unroll
  for (int mi = 0; mi < 2; ++mi)
#pragma unroll
    for (int ks2 = 0; ks2 < 2; ++ks2)
      af[mi][ks2] = *(const bf16x8*)&zsb[(size_t)(mtile0 + mi * 16 + rr) * 64 +
                                         ks2 * 32 + gq * 8];
  float bde[4];
#pragma unroll
  for (int nf = 0; nf < 4; ++nf) bde[nf] = bd[ncol0 + nf * 16 + rr];

  f32x4 acc[2][4];
#pragma unroll
  for (int mi = 0; mi < 2; ++mi)
#pragma unroll
    for (int nf = 0; nf < 4; ++nf) acc[mi][nf] = (f32x4){0.f, 0.f, 0.f, 0.f};

#pragma unroll
  for (int mi = 0; mi < 2; ++mi)
#pragma unroll
    for (int ks2 = 0; ks2 < 2; ++ks2)
#pragma unroll
      for (int nf = 0; nf < 4; ++nf)
        acc[mi][nf] = __builtin_amdgcn_mfma_f32_16x16x32_bf16(
            af[mi][ks2], bfr[ks2][nf], acc[mi][nf], 0, 0, 0);

  const int khi = (gq & 1) * 4;
#pragma unroll
  for (int mi = 0; mi < 2; ++mi) {
    const int bb = ((mtile0 + mi * 16) >> 3) + (gq >> 1);
#pragma unroll
    for (int nf = 0; nf < 4; ++nf) {
      const int col = ncol0 + nf * 16 + rr;
      float run = 0.f;
      float ov[4];
#pragma unroll
      for (int i = 0; i < 4; ++i) {
        float dec = acc[mi][nf][i] + bde[nf];
        float spd = softplus_fast(dec);
        ov[i] = run + (dec - spd);   // excl-cumsum(lns) + log_sigmoid(dec)
        run -= spd;                  // lns = -softplus(dec)
      }
      float prev = __shfl_xor(run, 16, 64);
      float base = (gq & 1) ? prev : 0.f;
#pragma unroll
      for (int i = 0; i < 4; ++i)
        out[((size_t)(khi + i) * NB + bb) * DN + col] = ov[i] + base;
    }
  }
}

extern "C" void kernel_launch(void* const* d_in, const int* in_sizes, int n_in,
                              void* d_out, int out_size, void* d_ws, size_t ws_size,
                              hipStream_t stream) {
  (void)in_sizes; (void)n_in; (void)out_size; (void)ws_size;
  const float* x     = (const float*)d_in[0];
  const float* eps0  = (const float*)d_in[2];
  const float* epsq  = (const float*)d_in[3];
  const float* Wstem = (const float*)d_in[5];
  const float* bstem = (const float*)d_in[6];
  const float* Wg    = (const float*)d_in[7];
  const float* bgp   = (const float*)d_in[8];
  const float* Wihq  = (const float*)d_in[9];
  const float* bq    = (const float*)d_in[10];
  const float* Wlinq = (const float*)d_in[11];
  const float* blinq = (const float*)d_in[12];
  const float* Wihp  = (const float*)d_in[13];
  const float* bp    = (const float*)d_in[14];
  const float* Wlinp = (const float*)d_in[15];
  const float* blinp = (const float*)d_in[16];
  const float* Wd    = (const float*)d_in[17];
  const float* bd    = (const float*)d_in[18];

  float* out    = (float*)d_out;
  float* outkl  = out + (size_t)KS * NB * DN;
  float* accbuf = (float*)d_ws;
  ushort* zsb   = (ushort*)(accbuf + NB * HD);
  ushort* wdt   = zsb + (size_t)KS * NB * ZD;
  ushort* wcombT = wdt + (size_t)DN * ZD;
  float* hfqg   = (float*)(wcombT + 640 * 512);
  float* enc0g  = hfqg + NB * HD;
  // split-K partials live in d_out's log_ms region (134 MB, dead until dec runs):
  float* part   = out;  // 64 * 256*512 f32 = 32 MB

  wdt_kernel<<<DN / 256, 256, 0, stream>>>(Wd, wdt);
  wcombT_kernel<<<dim3(10, 8), 256, 0, stream>>>(Wihq, Wg, wcombT);
  stem_kernel<<<dim3(8, SPLITS), 256, 0, stream>>>(x, Wstem, part);
  reduce_kernel<<<NB * HD / 4 / 256, 256, 0, stream>>>(part, accbuf);
  gemmA_kernel<<<dim3(10, 16), 256, 0, stream>>>(accbuf, bstem, wcombT, bq, bgp,
                                                 hfqg, enc0g);
  scan_kernel<<<NB, 512, 0, stream>>>(hfqg, enc0g, Wihq, Wihp, Wlinq, blinq,
                                      Wlinp, blinp, bp, eps0, epsq, zsb, outkl);
  dec_kernel<<<dim3(64, 64), 256, 0, stream>>>(zsb, wdt, bd, out);
}

// Round 7
// 160.069 us; speedup vs baseline: 2.3102x; 1.0181x over previous
//
#include <hip/hip_runtime.h>
#include <hip/hip_bf16.h>

#define ZD 64
#define HD 512
#define NB 256
#define KS 8
#define DIN 49152
#define DN 16384

typedef __attribute__((ext_vector_type(8))) short bf16x8;
typedef __attribute__((ext_vector_type(4))) float f32x4;

__device__ __forceinline__ ushort bfc(float x) {
  uint u = __float_as_uint(x);
  uint r = (u + 0x7FFFu + ((u >> 16) & 1u)) >> 16;
  return (ushort)r;
}
__device__ __forceinline__ uint pk2(float a, float b) {
  return (uint)bfc(a) | ((uint)bfc(b) << 16);
}
__device__ __forceinline__ float lof(uint u) { return __uint_as_float(u << 16); }
__device__ __forceinline__ float hif(uint u) { return __uint_as_float(u & 0xFFFF0000u); }
__device__ __forceinline__ float softplusf_(float x) {
  return fmaxf(x, 0.f) + log1pf(expf(-fabsf(x)));
}
__device__ __forceinline__ float softplus_fast(float x) {
  float e = __expf(-fabsf(x));
  return fmaxf(x, 0.f) + __logf(1.f + e);
}
__device__ __forceinline__ float sigmoidf_(float x) {
  return 1.f / (1.f + expf(-x));
}

// ---------------- Stem GEMM stage 1: partials[sp][b][h], NO atomics ----------------
// BM=128, BN=128, SPLITS=64 (K-chunk 768 = 12 K-steps), grid 8x64 = 512 blocks.
// Register prefetch double-buffer: iter t+1's 16 float4 in flight during iter t.
#define SPLITS 64
#define KCH (DIN / SPLITS) /* 768 */
#define BKK 64

struct PF {
  float4 a[8];
  float4 b[8];
};

__global__ __launch_bounds__(256, 2)
void stem_kernel(const float* __restrict__ x, const float* __restrict__ W,
                 float* __restrict__ part) {
  __shared__ ushort Ab[128][72];  // [row][k] bf16, 36 u32/row, granule-rotated
  __shared__ ushort Bt[128][72];  // transposed [n][k] bf16, granule-rotated
  const int mt = blockIdx.x >> 2, nt = blockIdx.x & 3;  // 2 x 4 tiles
  const int sp = blockIdx.y;                            // 0..63
  const int m0 = mt * 128, n0 = nt * 128;
  const int tid  = threadIdx.x;
  const int lane = tid & 63;
  const int wave = tid >> 6;                 // 4 waves
  const int wm = wave >> 1, wn = wave & 1;   // wave tile: 64 x 64

  f32x4 accr[4][4];
#pragma unroll
  for (int i = 0; i < 4; ++i)
#pragma unroll
    for (int j = 0; j < 4; ++j) accr[i][j] = (f32x4){0.f, 0.f, 0.f, 0.f};

  const int arow = tid >> 1, aq = tid & 1;   // A: 2 thr/row, 32 f32 each
  const int bnb = tid & 31, kb = tid >> 5;   // B: col-group, 8-row k-group
  const int rr = lane & 15, gq = lane >> 4;

  const float* asrc0 = x + (size_t)(m0 + arow) * DIN + aq * 32;
  const float* bsrc0 = W + (size_t)kb * 8 * HD + n0 + bnb * 4;

  auto pf_load = [&](PF& p, int k0) {
    const float4* src = (const float4*)(asrc0 + k0);
#pragma unroll
    for (int j = 0; j < 8; ++j) p.a[j] = src[j];
#pragma unroll
    for (int i = 0; i < 8; ++i)
      p.b[i] = *(const float4*)(bsrc0 + (size_t)(k0 + i) * HD);
  };
  auto pf_stage = [&](const PF& p) {
    uint* base = (uint*)&Ab[0][0] + arow * 36;
#pragma unroll
    for (int j = 0; j < 8; ++j) {
      float4 v = p.a[j];
      const int off = ((aq * 2 + (j >> 2) + arow) & 3) * 8 + (j & 3) * 2;
      *(uint2*)(base + off) = make_uint2(pk2(v.x, v.y), pk2(v.z, v.w));
    }
    const float* q = (const float*)p.b;
#pragma unroll
    for (int c = 0; c < 4; ++c) {
      const int row = bnb * 4 + c;
      const int off = row * 36 + (((kb >> 1) + row) & 3) * 8 + (kb & 1) * 4;
      *(uint4*)((uint*)&Bt[0][0] + off) =
          make_uint4(pk2(q[0 * 4 + c], q[1 * 4 + c]), pk2(q[2 * 4 + c], q[3 * 4 + c]),
                     pk2(q[4 * 4 + c], q[5 * 4 + c]), pk2(q[6 * 4 + c], q[7 * 4 + c]));
    }
  };
  auto compute = [&]() {
#pragma unroll
    for (int ks = 0; ks < 2; ++ks) {
      const int q = 2 * ks + (gq >> 1);
      const int sub = (gq & 1) * 4;
      bf16x8 af[4], bfr[4];
#pragma unroll
      for (int mf = 0; mf < 4; ++mf) {
        const int row = wm * 64 + mf * 16 + rr;
        af[mf] = *(const bf16x8*)((const uint*)&Ab[0][0] + row * 36 +
                                  ((q + row) & 3) * 8 + sub);
      }
#pragma unroll
      for (int nf = 0; nf < 4; ++nf) {
        const int rown = wn * 64 + nf * 16 + rr;
        bfr[nf] = *(const bf16x8*)((const uint*)&Bt[0][0] + rown * 36 +
                                   ((q + rown) & 3) * 8 + sub);
      }
#pragma unroll
      for (int mf = 0; mf < 4; ++mf)
#pragma unroll
        for (int nf = 0; nf < 4; ++nf)
          accr[mf][nf] = __builtin_amdgcn_mfma_f32_16x16x32_bf16(
              af[mf], bfr[nf], accr[mf][nf], 0, 0, 0);
    }
  };

  const int kbase = sp * KCH;
  PF p0, p1;
  pf_load(p0, kbase);
#pragma unroll 1
  for (int tr = 0; tr < 6; ++tr) {
    const int it = 2 * tr;
    pf_load(p1, kbase + (it + 1) * BKK);   // in flight across stage+compute of p0
    __syncthreads();
    pf_stage(p0);
    __syncthreads();
    compute();
    if (tr < 5) pf_load(p0, kbase + (it + 2) * BKK);  // in flight across p1's phase
    __syncthreads();
    pf_stage(p1);
    __syncthreads();
    compute();
  }

  // C/D layout: col = lane&15, row = 4*(lane>>4)+i ; plain coalesced stores
  const int ccol = lane & 15, crow = (lane >> 4) * 4;
  float* base = part + (size_t)sp * (NB * HD);
#pragma unroll
  for (int mf = 0; mf < 4; ++mf) {
#pragma unroll
    for (int nf = 0; nf < 4; ++nf) {
      const int col = n0 + wn * 64 + nf * 16 + ccol;
      const int row = m0 + wm * 64 + mf * 16 + crow;
#pragma unroll
      for (int i = 0; i < 4; ++i)
        base[(size_t)(row + i) * HD + col] = accr[mf][nf][i];
    }
  }
}

// ---------------- Stem stage 2: acc = sum over 64 splits ----------------
__global__ __launch_bounds__(256)
void reduce_kernel(const float* __restrict__ part, float* __restrict__ acc) {
  const int idx = blockIdx.x * 256 + threadIdx.x;  // float4 index, 32768 total
  const float4* p = (const float4*)part;
  float4 s = p[idx];
#pragma unroll 8
  for (int sp = 1; sp < SPLITS; ++sp) {
    float4 v = p[(size_t)sp * (NB * HD / 4) + idx];
    s.x += v.x; s.y += v.y; s.z += v.z; s.w += v.w;
  }
  ((float4*)acc)[idx] = s;
}

// ---- WcombT: bf16 [640 cols][512 k] of B = [Wihq[:512] | Wg] ----
__global__ __launch_bounds__(256)
void wcombT_kernel(const float* __restrict__ Wihq, const float* __restrict__ Wg,
                   ushort* __restrict__ WcT) {
  __shared__ float T[64][68];
  const int bx = blockIdx.x;
  const int by = blockIdx.y;
  const int t = threadIdx.x;
  const int ct = bx * 64, kt = by * 64;
  {
    const int rl = t >> 2, cq = (t & 3) * 16;
    const float* src = (bx < 8) ? &Wihq[(size_t)(kt + rl) * 512 + ct + cq]
                                : &Wg[(size_t)(kt + rl) * 128 + (ct - 512) + cq];
#pragma unroll
    for (int i = 0; i < 4; ++i) {
      float4 v = *(const float4*)(src + 4 * i);
      T[rl][cq + 4 * i + 0] = v.x;
      T[rl][cq + 4 * i + 1] = v.y;
      T[rl][cq + 4 * i + 2] = v.z;
      T[rl][cq + 4 * i + 3] = v.w;
    }
  }
  __syncthreads();
  {
    const int cl = t >> 2, kq = (t & 3) * 16;
    uint* dst = (uint*)WcT;
#pragma unroll
    for (int i = 0; i < 8; ++i) {
      uint u = pk2(T[kq + 2 * i][cl], T[kq + 2 * i + 1][cl]);
      dst[(((size_t)(ct + cl)) * 512 + kt + kq + 2 * i) >> 1] = u;
    }
  }
}

// ---- gemmA: hf = relu(acc+bstem); hfqg = hf@Wihq[:512]+bq ; enc0g = hf@Wg+bg ----
__global__ __launch_bounds__(256)
void gemmA_kernel(const float* __restrict__ acc, const float* __restrict__ bstem,
                  const ushort* __restrict__ WcT, const float* __restrict__ bq,
                  const float* __restrict__ bg, float* __restrict__ hfqg,
                  float* __restrict__ enc0g) {
  const int tid = threadIdx.x;
  const int lane = tid & 63;
  const int wave = tid >> 6;
  const int rr = lane & 15, gq = lane >> 4;
  const int mtile = blockIdx.y * 16;
  const int ncol = blockIdx.x * 64 + wave * 16;
  const int row = mtile + rr;

  f32x4 a4 = (f32x4){0.f, 0.f, 0.f, 0.f};
#pragma unroll
  for (int ks2 = 0; ks2 < 16; ++ks2) {
    const int k0 = ks2 * 32 + gq * 8;
    float4 x0 = *(const float4*)&acc[(size_t)row * HD + k0];
    float4 x1 = *(const float4*)&acc[(size_t)row * HD + k0 + 4];
    float4 b0 = *(const float4*)&bstem[k0];
    float4 b1 = *(const float4*)&bstem[k0 + 4];
    bf16x8 af;
    af[0] = (short)bfc(fmaxf(x0.x + b0.x, 0.f));
    af[1] = (short)bfc(fmaxf(x0.y + b0.y, 0.f));
    af[2] = (short)bfc(fmaxf(x0.z + b0.z, 0.f));
    af[3] = (short)bfc(fmaxf(x0.w + b0.w, 0.f));
    af[4] = (short)bfc(fmaxf(x1.x + b1.x, 0.f));
    af[5] = (short)bfc(fmaxf(x1.y + b1.y, 0.f));
    af[6] = (short)bfc(fmaxf(x1.z + b1.z, 0.f));
    af[7] = (short)bfc(fmaxf(x1.w + b1.w, 0.f));
    bf16x8 bf = *(const bf16x8*)&WcT[(size_t)(ncol + rr) * 512 + k0];
    a4 = __builtin_amdgcn_mfma_f32_16x16x32_bf16(af, bf, a4, 0, 0, 0);
  }
  const int col = ncol + rr;
  if (col < 512) {
    const float bb = bq[col];
#pragma unroll
    for (int i = 0; i < 4; ++i)
      hfqg[(size_t)(mtile + 4 * gq + i) * HD + col] = a4[i] + bb;
  } else {
    const float bb = bg[col - 512];
#pragma unroll
    for (int i = 0; i < 4; ++i)
      enc0g[(size_t)(mtile + 4 * gq + i) * 128 + (col - 512)] = a4[i] + bb;
  }
}

// ---------------- Recurrent scan: one block (512 thr) per batch row ----------------
__global__ __launch_bounds__(512, 2)
void scan_kernel(const float* __restrict__ hfqg, const float* __restrict__ enc0g,
                 const float* __restrict__ Wihq, const float* __restrict__ Wihp,
                 const float* __restrict__ Wlinq, const float* __restrict__ blinq,
                 const float* __restrict__ Wlinp, const float* __restrict__ blinp,
                 const float* __restrict__ bp,
                 const float* __restrict__ eps0, const float* __restrict__ epsq,
                 ushort* __restrict__ zsb, float* __restrict__ out_kl) {
  const int b = blockIdx.x, tid = threadIdx.x;
  __shared__ uint WlL[2][64 * 128];
  __shared__ float g[512], gp[512];
  __shared__ float hq[128], hp[128];
  __shared__ float psum[512];
  __shared__ float zsh[64];
  __shared__ float epsL[448];

  uint wq[32], wp[32];
#pragma unroll
  for (int zp = 0; zp < 32; ++zp) {
    wq[zp] = pk2(Wihq[(size_t)(HD + 2 * zp) * HD + tid],
                 Wihq[(size_t)(HD + 2 * zp + 1) * HD + tid]);
    wp[zp] = pk2(Wihp[(size_t)(2 * zp) * HD + tid],
                 Wihp[(size_t)(2 * zp + 1) * HD + tid]);
  }
#pragma unroll
  for (int i = 0; i < 16; ++i) {
    int idx = i * 512 + tid;
    int kp2 = idx >> 7, jj = idx & 127;
    WlL[0][idx] = pk2(Wlinq[(2 * kp2) * 128 + jj], Wlinq[(2 * kp2 + 1) * 128 + jj]);
    WlL[1][idx] = pk2(Wlinp[(2 * kp2) * 128 + jj], Wlinp[(2 * kp2 + 1) * 128 + jj]);
  }
  if (tid < 448) epsL[tid] = epsq[(size_t)((tid >> 6) * NB + b) * ZD + (tid & 63)];
  const float hfq_reg = hfqg[(size_t)b * HD + tid];
  const float bp_reg = bp[tid];
  if (tid < 64) {
    float mu = enc0g[b * 128 + tid], lv = enc0g[b * 128 + 64 + tid];
    float s0 = softplusf_(lv + 0.5f) + 1e-8f;
    float z0 = mu + s0 * eps0[b * ZD + tid];
    zsh[tid] = z0;
    zsb[(b * KS) * ZD + tid] = bfc(z0);
    out_kl[(b * ZD + tid) * KS] = -logf(s0) + (s0 * s0 + mu * mu) * 0.5f - 0.5f;
  }
  __syncthreads();

  for (int t = 0; t < KS - 1; ++t) {
    float aq = hfq_reg, ap = bp_reg;
#pragma unroll
    for (int zp = 0; zp < 32; ++zp) {
      float z0v = zsh[2 * zp], z1v = zsh[2 * zp + 1];
      uint uq = wq[zp], up = wp[zp];
      aq += z0v * lof(uq) + z1v * hif(uq);
      ap += z0v * lof(up) + z1v * hif(up);
    }
    g[tid] = aq;
    gp[tid] = ap;
    __syncthreads();
    if (tid < 128) {
      float cs = sigmoidf_(g[tid]) * tanhf(g[256 + tid]);
      hq[tid] = sigmoidf_(g[384 + tid]) * tanhf(cs);
    } else if (tid < 256) {
      int j = tid & 127;
      float cs = sigmoidf_(gp[j]) * tanhf(gp[256 + j]);
      hp[j] = sigmoidf_(gp[384 + j]) * tanhf(cs);
    }
    __syncthreads();
    {
      int s = tid & 255, jj = s & 127, kc = s >> 7;
      int mq_ = tid >> 8;
      const float* h = mq_ ? hp : hq;
      const uint* W = WlL[mq_];
      float a = 0.f;
#pragma unroll
      for (int kp = 0; kp < 32; ++kp) {
        uint u = W[(kc * 32 + kp) * 128 + jj];
        a += h[kc * 64 + 2 * kp] * lof(u) + h[kc * 64 + 2 * kp + 1] * hif(u);
      }
      psum[tid] = a;
    }
    __syncthreads();
    if (tid < 64) {
      float mq = psum[tid] + psum[128 + tid] + blinq[tid];
      float lq = psum[64 + tid] + psum[192 + tid] + blinq[64 + tid];
      float sq = softplusf_(lq + 0.5f) + 1e-8f;
      float zq = mq + sq * epsL[t * 64 + tid];
      float mp2 = psum[256 + tid] + psum[384 + tid] + blinp[tid];
      float lp = psum[320 + tid] + psum[448 + tid] + blinp[64 + tid];
      float sp_ = softplusf_(lp + 0.5f) + 1e-8f;
      float d = mq - mp2;
      out_kl[(b * ZD + tid) * KS + t + 1] =
          logf(sp_ / sq) + (sq * sq + d * d) / (2.f * sp_ * sp_) - 0.5f;
      zsb[(b * KS + t + 1) * ZD + tid] = bfc(zq);
      zsh[tid] = zq;
    }
    __syncthreads();
  }
}

// -------- W_dec transpose to bf16 --------
__global__ __launch_bounds__(256)
void wdt_kernel(const float* __restrict__ Wd, ushort* __restrict__ WdT) {
  const int c = blockIdx.x * 256 + threadIdx.x;
  uint packed[32];
#pragma unroll
  for (int k = 0; k < 32; ++k) {
    float a = Wd[(size_t)(2 * k) * DN + c];
    float b = Wd[(size_t)(2 * k + 1) * DN + c];
    packed[k] = pk2(a, b);
  }
  uint4* dst = (uint4*)&WdT[(size_t)c * 64];
#pragma unroll
  for (int i = 0; i < 8; ++i)
    dst[i] = make_uint4(packed[4 * i], packed[4 * i + 1], packed[4 * i + 2],
                        packed[4 * i + 3]);
}

// -------- Decoder: MFMA + log-sigmoid + excl k-cumsum. 2 m-tiles/block, ILP-hoisted --------
__global__ __launch_bounds__(256)
void dec_kernel(const ushort* __restrict__ zsb, const ushort* __restrict__ WdT,
                const float* __restrict__ bd, float* __restrict__ out) {
  const int tid = threadIdx.x;
  const int lane = tid & 63;
  const int wave = tid >> 6;
  const int rr = lane & 15, gq = lane >> 4;
  const int mtile0 = blockIdx.y * 32;              // 2048/32 = 64
  const int ncol0 = blockIdx.x * 256 + wave * 64;  // 16384/256 = 64

  bf16x8 bfr[2][4];
#pragma unroll
  for (int ks2 = 0; ks2 < 2; ++ks2)
#pragma unroll
    for (int nf = 0; nf < 4; ++nf)
      bfr[ks2][nf] = *(const bf16x8*)&WdT[(size_t)(ncol0 + nf * 16 + rr) * 64 +
                                          ks2 * 32 + gq * 8];
  bf16x8 af[2][2];
#pragma unroll
  for (int mi = 0; mi < 2; ++mi)
#pragma unroll
    for (int ks2 = 0; ks2 < 2; ++ks2)
      af[mi][ks2] = *(const bf16x8*)&zsb[(size_t)(mtile0 + mi * 16 + rr) * 64 +
                                         ks2 * 32 + gq * 8];
  float bde[4];
#pragma unroll
  for (int nf = 0; nf < 4; ++nf) bde[nf] = bd[ncol0 + nf * 16 + rr];

  f32x4 acc[2][4];
#pragma unroll
  for (int mi = 0; mi < 2; ++mi)
#pragma unroll
    for (int nf = 0; nf < 4; ++nf) acc[mi][nf] = (f32x4){0.f, 0.f, 0.f, 0.f};

#pragma unroll
  for (int mi = 0; mi < 2; ++mi)
#pragma unroll
    for (int ks2 = 0; ks2 < 2; ++ks2)
#pragma unroll
      for (int nf = 0; nf < 4; ++nf)
        acc[mi][nf] = __builtin_amdgcn_mfma_f32_16x16x32_bf16(
            af[mi][ks2], bfr[ks2][nf], acc[mi][nf], 0, 0, 0);

  const int khi = (gq & 1) * 4;
#pragma unroll
  for (int mi = 0; mi < 2; ++mi) {
    const int bb = ((mtile0 + mi * 16) >> 3) + (gq >> 1);
#pragma unroll
    for (int nf = 0; nf < 4; ++nf) {
      const int col = ncol0 + nf * 16 + rr;
      float run = 0.f;
      float ov[4];
#pragma unroll
      for (int i = 0; i < 4; ++i) {
        float dec = acc[mi][nf][i] + bde[nf];
        float spd = softplus_fast(dec);
        ov[i] = run + (dec - spd);
        run -= spd;
      }
      float prev = __shfl_xor(run, 16, 64);
      float base = (gq & 1) ? prev : 0.f;
#pragma unroll
      for (int i = 0; i < 4; ++i)
        out[((size_t)(khi + i) * NB + bb) * DN + col] = ov[i] + base;
    }
  }
}

extern "C" void kernel_launch(void* const* d_in, const int* in_sizes, int n_in,
                              void* d_out, int out_size, void* d_ws, size_t ws_size,
                              hipStream_t stream) {
  (void)in_sizes; (void)n_in; (void)out_size; (void)ws_size;
  const float* x     = (const float*)d_in[0];
  const float* eps0  = (const float*)d_in[2];
  const float* epsq  = (const float*)d_in[3];
  const float* Wstem = (const float*)d_in[5];
  const float* bstem = (const float*)d_in[6];
  const float* Wg    = (const float*)d_in[7];
  const float* bgp   = (const float*)d_in[8];
  const float* Wihq  = (const float*)d_in[9];
  const float* bq    = (const float*)d_in[10];
  const float* Wlinq = (const float*)d_in[11];
  const float* blinq = (const float*)d_in[12];
  const float* Wihp  = (const float*)d_in[13];
  const float* bp    = (const float*)d_in[14];
  const float* Wlinp = (const float*)d_in[15];
  const float* blinp = (const float*)d_in[16];
  const float* Wd    = (const float*)d_in[17];
  const float* bd    = (const float*)d_in[18];

  float* out    = (float*)d_out;
  float* outkl  = out + (size_t)KS * NB * DN;
  float* accbuf = (float*)d_ws;
  ushort* zsb   = (ushort*)(accbuf + NB * HD);
  ushort* wdt   = zsb + (size_t)KS * NB * ZD;
  ushort* wcombT = wdt + (size_t)DN * ZD;
  float* hfqg   = (float*)(wcombT + 640 * 512);
  float* enc0g  = hfqg + NB * HD;
  // split-K partials live in d_out's log_ms region (134 MB, dead until dec runs):
  float* part   = out;  // 64 * 256*512 f32 = 32 MB

  wdt_kernel<<<DN / 256, 256, 0, stream>>>(Wd, wdt);
  wcombT_kernel<<<dim3(10, 8), 256, 0, stream>>>(Wihq, Wg, wcombT);
  stem_kernel<<<dim3(8, SPLITS), 256, 0, stream>>>(x, Wstem, part);
  reduce_kernel<<<NB * HD / 4 / 256, 256, 0, stream>>>(part, accbuf);
  gemmA_kernel<<<dim3(10, 16), 256, 0, stream>>>(accbuf, bstem, wcombT, bq, bgp,
                                                 hfqg, enc0g);
  scan_kernel<<<NB, 512, 0, stream>>>(hfqg, enc0g, Wihq, Wihp, Wlinq, blinq,
                                      Wlinp, blinp, bp, eps0, epsq, zsb, outkl);
  dec_kernel<<<dim3(64, 64), 256, 0, stream>>>(zsb, wdt, bd, out);
}